// Round 5
// baseline (1932.252 us; speedup 1.0000x reference)
//
#include <hip/hip_runtime.h>
#include <math.h>

// (B,S,DIM,H,KVH) = (2,1024,4096,32,8)
#define NB    2
#define NS    1024
#define NDIM  4096
#define NH    32
#define NKVH  8
#define NHD   128
#define NKVD  1024
#define NM    (NB*NS)            // 2048 rows
#define NQKV  (NDIM + 2*NKVD)    // 6144

typedef __attribute__((ext_vector_type(8))) short bf16x8;
typedef __attribute__((ext_vector_type(4))) float f32x4;

#define AS3(p) ((__attribute__((address_space(3))) void*)(p))
#define AS1(p) ((const __attribute__((address_space(1))) void*)(p))

__device__ __forceinline__ unsigned short f2bf(float f) {
  unsigned u = __builtin_bit_cast(unsigned, f);
  u += 0x7fffu + ((u >> 16) & 1u);
  return (unsigned short)(u >> 16);
}
__device__ __forceinline__ float bf2f(unsigned short h) {
  unsigned u = ((unsigned)h) << 16;
  return __builtin_bit_cast(float, u);
}
// v ~= hi + lo, ~16 mantissa bits total -> split-GEMM rel err ~1e-5
__device__ __forceinline__ void split2(float v, unsigned short& h, unsigned short& l) {
  h = f2bf(v);
  l = f2bf(v - bf2f(h));
}

// ---------------------------------------------------------------------------
// RMSNorm. OFMT 0: split bf16 hi/lo. OFMT 1: f32. One block per row.
// ---------------------------------------------------------------------------
template <int OFMT>
__global__ __launch_bounds__(256) void rmsnorm_k(const float* __restrict__ x,
                                                 const float* __restrict__ scale,
                                                 unsigned short* __restrict__ xnh,
                                                 unsigned short* __restrict__ xnl,
                                                 float* __restrict__ xnf) {
  const int row = blockIdx.x;
  const float4* xr = (const float4*)(x + (size_t)row * NDIM);
  const float4* sc4 = (const float4*)scale;
  const int t = threadIdx.x;
  float4 v[4];
  float ss = 0.f;
#pragma unroll
  for (int i = 0; i < 4; ++i) {
    v[i] = xr[t + 256 * i];
    ss += v[i].x * v[i].x + v[i].y * v[i].y + v[i].z * v[i].z + v[i].w * v[i].w;
  }
#pragma unroll
  for (int m = 32; m >= 1; m >>= 1) ss += __shfl_xor(ss, m, 64);
  __shared__ float red[4];
  if ((t & 63) == 0) red[t >> 6] = ss;
  __syncthreads();
  const float r = rsqrtf((red[0] + red[1] + red[2] + red[3]) * (1.0f / NDIM) + 1e-8f);
#pragma unroll
  for (int i = 0; i < 4; ++i) {
    const float4 s4 = sc4[t + 256 * i];
    float o[4] = {v[i].x * r * s4.x, v[i].y * r * s4.y, v[i].z * r * s4.z, v[i].w * r * s4.w};
    if (OFMT == 0) {
      ushort4 h4, l4;
      split2(o[0], h4.x, l4.x); split2(o[1], h4.y, l4.y);
      split2(o[2], h4.z, l4.z); split2(o[3], h4.w, l4.w);
      *(ushort4*)&xnh[(size_t)row * NDIM + (t + 256 * i) * 4] = h4;
      *(ushort4*)&xnl[(size_t)row * NDIM + (t + 256 * i) * 4] = l4;
    } else {
      *(float4*)&xnf[(size_t)row * NDIM + (t + 256 * i) * 4] =
          make_float4(o[0], o[1], o[2], o[3]);
    }
  }
}

// ---------------------------------------------------------------------------
// fp32 -> split bf16 flat (weights). count4 = elements/4.
// ---------------------------------------------------------------------------
__global__ __launch_bounds__(256) void splitw_k(const float* __restrict__ src,
                                                unsigned short* __restrict__ dh,
                                                unsigned short* __restrict__ dl,
                                                long long count4) {
  const long long stride = (long long)gridDim.x * 256;
  for (long long i = blockIdx.x * 256LL + threadIdx.x; i < count4; i += stride) {
    const float4 v = ((const float4*)src)[i];
    ushort4 h4, l4;
    split2(v.x, h4.x, l4.x); split2(v.y, h4.y, l4.y);
    split2(v.z, h4.z, l4.z); split2(v.w, h4.w, l4.w);
    ((ushort4*)dh)[i] = h4;
    ((ushort4*)dl)[i] = l4;
  }
}

__global__ __launch_bounds__(256) void zerofill_k(float* __restrict__ p, long long n) {
  const long long stride = (long long)gridDim.x * 256;
  for (long long i = blockIdx.x * 256LL + threadIdx.x; i < n; i += stride) p[i] = 0.f;
}

// ---------------------------------------------------------------------------
// Split-bf16 MFMA GEMM: C[m,n] = sum_k A[m,k]*W[n,k], K=4096.
// 128x128 tile, BK=32, 4 waves (2x2), wave = 64x64 = 4x4 frags of
// mfma_f32_16x16x32_bf16; split product hi*hi + hi*lo + lo*hi.
// global_load_lds w=16, linear LDS dest; 16B-slot XOR swizzle on BOTH global
// source (ke) and LDS read (idx) [rule #21]; slot' = seg ^ ((row>>1)&3).
// EPI 0: RoPE epilogue (abs col via ncol0; pairs adjacent -> shfl_xor(1)),
//        *1/sqrt(128) for Q cols; C stride 6144.
// EPI 1: out = acc + resid(hi+lo); C stride 4096.
// ---------------------------------------------------------------------------
template <int EPI>
__global__ __launch_bounds__(256) void gemm_split_k(
    const unsigned short* __restrict__ Ah, const unsigned short* __restrict__ Al,
    const unsigned short* __restrict__ Bh, const unsigned short* __restrict__ Bl,
    const float* __restrict__ fc, const float* __restrict__ fs,
    const unsigned short* __restrict__ resh, const unsigned short* __restrict__ resl,
    float* __restrict__ C, int ncol0) {
  constexpr int OW = (EPI == 0) ? NQKV : NDIM;
  __shared__ unsigned short lds[4][4096];  // Ah | Al | Bh | Bl tiles [128][32]

  const int t = threadIdx.x;
  const int wave = t >> 6, lane = t & 63;
  const int wr = wave >> 1, wc = wave & 1;
  const int m0 = blockIdx.x * 128;
  const int n0 = blockIdx.y * 128;

  const int srow = t >> 2;                             // 0..63
  const int ke = (((t & 3) ^ ((srow >> 1) & 3)) * 8);  // swizzled k-elem offset
  const size_t arow0 = (size_t)(m0 + srow) * NDIM + ke;
  const size_t arow1 = (size_t)(m0 + 64 + srow) * NDIM + ke;
  const size_t brow0 = (size_t)(n0 + srow) * NDIM + ke;
  const size_t brow1 = (size_t)(n0 + 64 + srow) * NDIM + ke;
  const int ldsoff0 = wave * 512;         // wave-uniform base (ushort idx)
  const int ldsoff1 = 2048 + wave * 512;

  f32x4 acc[4][4];
#pragma unroll
  for (int i = 0; i < 4; ++i)
#pragma unroll
    for (int j = 0; j < 4; ++j) acc[i][j] = (f32x4){0.f, 0.f, 0.f, 0.f};

  const int fl = lane & 15;
  const int fq = lane >> 4;

  for (int k0 = 0; k0 < NDIM; k0 += 32) {
    __syncthreads();
    __builtin_amdgcn_global_load_lds(AS1(Ah + arow0 + k0), AS3(&lds[0][ldsoff0]), 16, 0, 0);
    __builtin_amdgcn_global_load_lds(AS1(Ah + arow1 + k0), AS3(&lds[0][ldsoff1]), 16, 0, 0);
    __builtin_amdgcn_global_load_lds(AS1(Al + arow0 + k0), AS3(&lds[1][ldsoff0]), 16, 0, 0);
    __builtin_amdgcn_global_load_lds(AS1(Al + arow1 + k0), AS3(&lds[1][ldsoff1]), 16, 0, 0);
    __builtin_amdgcn_global_load_lds(AS1(Bh + brow0 + k0), AS3(&lds[2][ldsoff0]), 16, 0, 0);
    __builtin_amdgcn_global_load_lds(AS1(Bh + brow1 + k0), AS3(&lds[2][ldsoff1]), 16, 0, 0);
    __builtin_amdgcn_global_load_lds(AS1(Bl + brow0 + k0), AS3(&lds[3][ldsoff0]), 16, 0, 0);
    __builtin_amdgcn_global_load_lds(AS1(Bl + brow1 + k0), AS3(&lds[3][ldsoff1]), 16, 0, 0);
    __syncthreads();

    bf16x8 fah[4], fal[4], fbh[4], fbl[4];
#pragma unroll
    for (int m = 0; m < 4; ++m) {
      const int r = wr * 64 + m * 16 + fl;
      const int idx = r * 32 + ((fq ^ ((r >> 1) & 3)) * 8);
      fah[m] = *(const bf16x8*)&lds[0][idx];
      fal[m] = *(const bf16x8*)&lds[1][idx];
    }
#pragma unroll
    for (int n = 0; n < 4; ++n) {
      const int r = wc * 64 + n * 16 + fl;
      const int idx = r * 32 + ((fq ^ ((r >> 1) & 3)) * 8);
      fbh[n] = *(const bf16x8*)&lds[2][idx];
      fbl[n] = *(const bf16x8*)&lds[3][idx];
    }
#pragma unroll
    for (int m = 0; m < 4; ++m)
#pragma unroll
      for (int n = 0; n < 4; ++n) {
        acc[m][n] = __builtin_amdgcn_mfma_f32_16x16x32_bf16(fah[m], fbh[n], acc[m][n], 0, 0, 0);
        acc[m][n] = __builtin_amdgcn_mfma_f32_16x16x32_bf16(fah[m], fbl[n], acc[m][n], 0, 0, 0);
        acc[m][n] = __builtin_amdgcn_mfma_f32_16x16x32_bf16(fal[m], fbh[n], acc[m][n], 0, 0, 0);
      }
  }

  if (EPI == 0) {
    const int nabs0 = ncol0 + n0;
    const bool rope = (nabs0 < NDIM + NKVD);
    const float qs = (nabs0 < NDIM) ? 0.08838834764831845f : 1.0f;
#pragma unroll
    for (int m = 0; m < 4; ++m)
#pragma unroll
      for (int j = 0; j < 4; ++j) {
        const int gm = m0 + wr * 64 + m * 16 + fq * 4 + j;
        const int si = gm & (NS - 1);
        const float c = fc[si], s = fs[si];
#pragma unroll
        for (int n = 0; n < 4; ++n) {
          const int gn = nabs0 + wc * 64 + n * 16 + fl;
          const float val = acc[m][n][j];
          float o;
          if (rope) {
            const float par = __shfl_xor(val, 1, 64);  // partner col gn^1
            o = ((gn & 1) ? (val * c + par * s) : (val * c - par * s)) * qs;
          } else {
            o = val;
          }
          C[(size_t)gm * OW + gn] = o;
        }
      }
  } else {
#pragma unroll
    for (int m = 0; m < 4; ++m)
#pragma unroll
      for (int j = 0; j < 4; ++j) {
        const int gm = m0 + wr * 64 + m * 16 + fq * 4 + j;
#pragma unroll
        for (int n = 0; n < 4; ++n) {
          const int gn = n0 + wc * 64 + n * 16 + fl;
          const size_t ri = (size_t)gm * NDIM + gn;
          C[ri] = acc[m][n][j] + bf2f(resh[ri]) + bf2f(resl[ri]);
        }
      }
  }
}

// ---------------------------------------------------------------------------
// fp32 vector GEMM (PATH C fallback). C[m,n] = sum_k A[m,k]*W[n,k].
// 64x64 tile, BK=32, 4x4 microtile, LDS transposed [k][m] stride 68.
// EPI 0: fused QKV + RoPE. EPI 1: + f32 residual.
// ---------------------------------------------------------------------------
#define FBM 64
#define FBK 32
#define LPAD 68

template <int EPI>
__global__ __launch_bounds__(256) void gemm_f32_k(const float* __restrict__ A,
                                                  const float* __restrict__ Wq,
                                                  const float* __restrict__ Wk,
                                                  const float* __restrict__ Wv,
                                                  const float* __restrict__ fc,
                                                  const float* __restrict__ fs,
                                                  const float* __restrict__ resid,
                                                  float* __restrict__ C) {
  __shared__ float As[FBK][LPAD];
  __shared__ float Bs[FBK][LPAD];
  const int t = threadIdx.x;
  const int tx = t & 15, ty = t >> 4;
  const int m0 = blockIdx.y * FBM;
  const int n0 = blockIdx.x * FBM;

  const float* W;
  int wn0;
  if (EPI == 0) {
    if (n0 < NDIM)              { W = Wq; wn0 = n0; }
    else if (n0 < NDIM + NKVD)  { W = Wk; wn0 = n0 - NDIM; }
    else                        { W = Wv; wn0 = n0 - NDIM - NKVD; }
  } else {
    W = Wq; wn0 = n0;  // Wq slot carries wo
  }

  const int srow = t >> 3;
  const int skk  = (t & 7) * 4;
  const float* Ar = A + (size_t)(m0 + srow) * NDIM + skk;
  const float* Br = W + (size_t)(wn0 + srow) * NDIM + skk;

  float acc[4][4] = {};

  for (int k0 = 0; k0 < NDIM; k0 += FBK) {
    const float4 a0 = *(const float4*)(Ar + k0);
    const float4 a1 = *(const float4*)(Ar + k0 + (size_t)32 * NDIM);
    const float4 b0 = *(const float4*)(Br + k0);
    const float4 b1 = *(const float4*)(Br + k0 + (size_t)32 * NDIM);
    __syncthreads();
    As[skk + 0][srow] = a0.x; As[skk + 1][srow] = a0.y;
    As[skk + 2][srow] = a0.z; As[skk + 3][srow] = a0.w;
    As[skk + 0][srow + 32] = a1.x; As[skk + 1][srow + 32] = a1.y;
    As[skk + 2][srow + 32] = a1.z; As[skk + 3][srow + 32] = a1.w;
    Bs[skk + 0][srow] = b0.x; Bs[skk + 1][srow] = b0.y;
    Bs[skk + 2][srow] = b0.z; Bs[skk + 3][srow] = b0.w;
    Bs[skk + 0][srow + 32] = b1.x; Bs[skk + 1][srow + 32] = b1.y;
    Bs[skk + 2][srow + 32] = b1.z; Bs[skk + 3][srow + 32] = b1.w;
    __syncthreads();
#pragma unroll
    for (int k = 0; k < FBK; ++k) {
      const float4 a = *(const float4*)&As[k][ty * 4];
      const float4 b = *(const float4*)&Bs[k][tx * 4];
      const float av[4] = {a.x, a.y, a.z, a.w};
      const float bv[4] = {b.x, b.y, b.z, b.w};
#pragma unroll
      for (int i = 0; i < 4; ++i)
#pragma unroll
        for (int j = 0; j < 4; ++j)
          acc[i][j] = fmaf(av[i], bv[j], acc[i][j]);
    }
  }

  if (EPI == 0) {
    const bool rope = (n0 < NDIM + NKVD);
    const float qs = (n0 < NDIM) ? 0.08838834764831845f : 1.0f;
#pragma unroll
    for (int i = 0; i < 4; ++i) {
      const int m = m0 + ty * 4 + i;
      const int s = m & (NS - 1);
      const float c = fc[s], sn = fs[s];
      float4 o;
      if (rope) {
        o.x = (acc[i][0] * c - acc[i][1] * sn) * qs;
        o.y = (acc[i][0] * sn + acc[i][1] * c) * qs;
        o.z = (acc[i][2] * c - acc[i][3] * sn) * qs;
        o.w = (acc[i][2] * sn + acc[i][3] * c) * qs;
      } else {
        o = make_float4(acc[i][0], acc[i][1], acc[i][2], acc[i][3]);
      }
      *(float4*)(C + (size_t)m * NQKV + n0 + tx * 4) = o;
    }
  } else {
#pragma unroll
    for (int i = 0; i < 4; ++i) {
      const int m = m0 + ty * 4 + i;
      const float4 r4 = *(const float4*)(resid + (size_t)m * NDIM + n0 + tx * 4);
      *(float4*)(C + (size_t)m * NDIM + n0 + tx * 4) =
          make_float4(acc[i][0] + r4.x, acc[i][1] + r4.y, acc[i][2] + r4.z, acc[i][3] + r4.w);
    }
  }
}

// ---------------------------------------------------------------------------
// Causal flash attention, fp32 VALU. OFMT 0: split-bf16 out. OFMT 1: f32 out.
// GQA per jnp.tile: kvh = h % 8. Q pre-scaled by 1/sqrt(128).
// ---------------------------------------------------------------------------
#define BQ 32
#define BKV 32
#define KPAD 132

template <int OFMT>
__global__ __launch_bounds__(256) void attn_k(const float* __restrict__ qkv,
                                              unsigned short* __restrict__ aoh,
                                              unsigned short* __restrict__ aol,
                                              float* __restrict__ aof) {
  const int qt = blockIdx.x;
  const int bh = blockIdx.y;
  const int b = bh >> 5;
  const int h = bh & 31;
  const int kvh = h & 7;

  __shared__ float Qs[BQ][KPAD];
  __shared__ float Ks[BKV][KPAD];
  __shared__ float Vs[BKV][KPAD];
  __shared__ float Ps[BQ][BKV + 1];

  const int t = threadIdx.x;
  const int lane8 = t & 7;
  const int qi = t >> 3;
  const int q0 = qt * BQ;

  {
    const float* qrow = qkv + (size_t)(b * NS + q0 + qi) * NQKV + h * NHD + lane8 * 16;
#pragma unroll
    for (int i = 0; i < 4; ++i)
      *(float4*)&Qs[qi][lane8 * 16 + 4 * i] = *(const float4*)(qrow + 4 * i);
  }

  float m_run = -INFINITY, l_run = 0.f;
  float4 o0 = {0,0,0,0}, o1 = {0,0,0,0}, o2 = {0,0,0,0}, o3 = {0,0,0,0};

  const size_t kbase = (size_t)(b * NS) * NQKV + NDIM + (size_t)kvh * NHD;
  const size_t vbase = kbase + NKVD;

  for (int jt = 0; jt <= qt; ++jt) {
    const int kv0 = jt * BKV;
    const float* kr = qkv + kbase + (size_t)(kv0 + qi) * NQKV + lane8 * 16;
    const float* vr = qkv + vbase + (size_t)(kv0 + qi) * NQKV + lane8 * 16;
    __syncthreads();
#pragma unroll
    for (int i = 0; i < 4; ++i) {
      *(float4*)&Ks[qi][lane8 * 16 + 4 * i] = *(const float4*)(kr + 4 * i);
      *(float4*)&Vs[qi][lane8 * 16 + 4 * i] = *(const float4*)(vr + 4 * i);
    }
    __syncthreads();

    float scv[4] = {0.f, 0.f, 0.f, 0.f};
#pragma unroll
    for (int d4 = 0; d4 < NHD / 4; ++d4) {
      const float4 q4 = *(const float4*)&Qs[qi][4 * d4];
#pragma unroll
      for (int j = 0; j < 4; ++j) {
        const float4 k4 = *(const float4*)&Ks[lane8 + 8 * j][4 * d4];
        scv[j] = fmaf(q4.x, k4.x, fmaf(q4.y, k4.y, fmaf(q4.z, k4.z, fmaf(q4.w, k4.w, scv[j]))));
      }
    }
    if (jt == qt) {
#pragma unroll
      for (int j = 0; j < 4; ++j)
        if (lane8 + 8 * j > qi) scv[j] = -INFINITY;
    }

    float mloc = fmaxf(fmaxf(scv[0], scv[1]), fmaxf(scv[2], scv[3]));
#pragma unroll
    for (int mm = 1; mm <= 4; mm <<= 1) mloc = fmaxf(mloc, __shfl_xor(mloc, mm, 64));
    const float m_new = fmaxf(m_run, mloc);
    const float resc = __expf(m_run - m_new);
    float p[4], psum = 0.f;
#pragma unroll
    for (int j = 0; j < 4; ++j) { p[j] = __expf(scv[j] - m_new); psum += p[j]; }
#pragma unroll
    for (int mm = 1; mm <= 4; mm <<= 1) psum += __shfl_xor(psum, mm, 64);
    l_run = l_run * resc + psum;
    m_run = m_new;
    o0.x *= resc; o0.y *= resc; o0.z *= resc; o0.w *= resc;
    o1.x *= resc; o1.y *= resc; o1.z *= resc; o1.w *= resc;
    o2.x *= resc; o2.y *= resc; o2.z *= resc; o2.w *= resc;
    o3.x *= resc; o3.y *= resc; o3.z *= resc; o3.w *= resc;
#pragma unroll
    for (int j = 0; j < 4; ++j) Ps[qi][lane8 + 8 * j] = p[j];
    __syncthreads();

#pragma unroll
    for (int kk = 0; kk < BKV; ++kk) {
      const float pv = Ps[qi][kk];
      const float4 v0 = *(const float4*)&Vs[kk][lane8 * 4];
      const float4 v1 = *(const float4*)&Vs[kk][lane8 * 4 + 32];
      const float4 v2 = *(const float4*)&Vs[kk][lane8 * 4 + 64];
      const float4 v3 = *(const float4*)&Vs[kk][lane8 * 4 + 96];
      o0.x = fmaf(pv, v0.x, o0.x); o0.y = fmaf(pv, v0.y, o0.y);
      o0.z = fmaf(pv, v0.z, o0.z); o0.w = fmaf(pv, v0.w, o0.w);
      o1.x = fmaf(pv, v1.x, o1.x); o1.y = fmaf(pv, v1.y, o1.y);
      o1.z = fmaf(pv, v1.z, o1.z); o1.w = fmaf(pv, v1.w, o1.w);
      o2.x = fmaf(pv, v2.x, o2.x); o2.y = fmaf(pv, v2.y, o2.y);
      o2.z = fmaf(pv, v2.z, o2.z); o2.w = fmaf(pv, v2.w, o2.w);
      o3.x = fmaf(pv, v3.x, o3.x); o3.y = fmaf(pv, v3.y, o3.y);
      o3.z = fmaf(pv, v3.z, o3.z); o3.w = fmaf(pv, v3.w, o3.w);
    }
  }

  const float inv_l = 1.0f / l_run;
  const size_t rowb = (size_t)(b * NS + q0 + qi) * NDIM + h * NHD;
  const float4 ws[4] = {
      make_float4(o0.x * inv_l, o0.y * inv_l, o0.z * inv_l, o0.w * inv_l),
      make_float4(o1.x * inv_l, o1.y * inv_l, o1.z * inv_l, o1.w * inv_l),
      make_float4(o2.x * inv_l, o2.y * inv_l, o2.z * inv_l, o2.w * inv_l),
      make_float4(o3.x * inv_l, o3.y * inv_l, o3.z * inv_l, o3.w * inv_l)};
#pragma unroll
  for (int jj = 0; jj < 4; ++jj) {
    if (OFMT == 0) {
      ushort4 h4, l4;
      split2(ws[jj].x, h4.x, l4.x); split2(ws[jj].y, h4.y, l4.y);
      split2(ws[jj].z, h4.z, l4.z); split2(ws[jj].w, h4.w, l4.w);
      *(ushort4*)&aoh[rowb + lane8 * 4 + 32 * jj] = h4;
      *(ushort4*)&aol[rowb + lane8 * 4 + 32 * jj] = l4;
    } else {
      *(float4*)&aof[rowb + lane8 * 4 + 32 * jj] = ws[jj];
    }
  }
}

// ---------------------------------------------------------------------------
extern "C" void kernel_launch(void* const* d_in, const int* in_sizes, int n_in,
                              void* d_out, int out_size, void* d_ws, size_t ws_size,
                              hipStream_t stream) {
  const float* x  = (const float*)d_in[0];
  const float* sc = (const float*)d_in[1];
  const float* wq = (const float*)d_in[2];
  const float* wk = (const float*)d_in[3];
  const float* wv = (const float*)d_in[4];
  const float* wo = (const float*)d_in[5];
  const float* fc = (const float*)d_in[6];
  const float* fs = (const float*)d_in[7];
  float* out = (float*)d_out;

  const size_t bf = (size_t)NM * NDIM * 2;          // 16.78 MB (one bf16 plane)
  const size_t qkvB = (size_t)NM * NQKV * 4;        // 50.33 MB
  const size_t needA = 4 * bf + qkvB + (size_t)NQKV * NDIM * 4;  // 218.10 MB
  const size_t needB = 4 * bf + qkvB + (size_t)NDIM * NDIM * 4;  // 184.55 MB
  const size_t needC = 2 * (size_t)NM * NDIM * 4 + qkvB;         // 117.44 MB

  if (ws_size >= needB) {
    // ---- split-bf16 MFMA pipeline (PATH A fused / PATH B sequenced) ----
    unsigned short* xnh = (unsigned short*)d_ws;
    unsigned short* xnl = xnh + (size_t)NM * NDIM;
    float* qkv = (float*)(xnl + (size_t)NM * NDIM);
    unsigned short* aoh = (unsigned short*)(qkv + (size_t)NM * NQKV);
    unsigned short* aol = aoh + (size_t)NM * NDIM;
    unsigned short* wh  = aol + (size_t)NM * NDIM;

    rmsnorm_k<0><<<NM, 256, 0, stream>>>(x, sc, xnh, xnl, nullptr);

    if (ws_size >= needA) {  // PATH A: fused QKV weight split
      unsigned short* wl = wh + (size_t)NQKV * NDIM;
      splitw_k<<<1024, 256, 0, stream>>>(wq, wh, wl, (long long)NDIM * NDIM / 4);
      splitw_k<<<1024, 256, 0, stream>>>(wk, wh + (size_t)NDIM * NDIM,
                                         wl + (size_t)NDIM * NDIM, (long long)NKVD * NDIM / 4);
      splitw_k<<<1024, 256, 0, stream>>>(wv, wh + (size_t)(NDIM + NKVD) * NDIM,
                                         wl + (size_t)(NDIM + NKVD) * NDIM,
                                         (long long)NKVD * NDIM / 4);
      gemm_split_k<0><<<dim3(NM / 128, NQKV / 128), 256, 0, stream>>>(
          xnh, xnl, wh, wl, fc, fs, nullptr, nullptr, qkv, 0);
      attn_k<0><<<dim3(NS / BQ, NB * NH), 256, 0, stream>>>(qkv, aoh, aol, nullptr);
      splitw_k<<<1024, 256, 0, stream>>>(wo, wh, wl, (long long)NDIM * NDIM / 4);
      gemm_split_k<1><<<dim3(NM / 128, NDIM / 128), 256, 0, stream>>>(
          aoh, aol, wh, wl, nullptr, nullptr, xnh, xnl, out, 0);
    } else {  // PATH B: sequence Q / KV / O through one 67 MB weight buffer
      unsigned short* wl = wh + (size_t)NDIM * NDIM;
      splitw_k<<<1024, 256, 0, stream>>>(wq, wh, wl, (long long)NDIM * NDIM / 4);
      gemm_split_k<0><<<dim3(NM / 128, NDIM / 128), 256, 0, stream>>>(
          xnh, xnl, wh, wl, fc, fs, nullptr, nullptr, qkv, 0);
      splitw_k<<<1024, 256, 0, stream>>>(wk, wh, wl, (long long)NKVD * NDIM / 4);
      splitw_k<<<1024, 256, 0, stream>>>(wv, wh + (size_t)NKVD * NDIM,
                                         wl + (size_t)NKVD * NDIM, (long long)NKVD * NDIM / 4);
      gemm_split_k<0><<<dim3(NM / 128, (2 * NKVD) / 128), 256, 0, stream>>>(
          xnh, xnl, wh, wl, fc, fs, nullptr, nullptr, qkv, NDIM);
      attn_k<0><<<dim3(NS / BQ, NB * NH), 256, 0, stream>>>(qkv, aoh, aol, nullptr);
      splitw_k<<<1024, 256, 0, stream>>>(wo, wh, wl, (long long)NDIM * NDIM / 4);
      gemm_split_k<1><<<dim3(NM / 128, NDIM / 128), 256, 0, stream>>>(
          aoh, aol, wh, wl, nullptr, nullptr, xnh, xnl, out, 0);
    }
  } else if (ws_size >= needC) {
    // ---- PATH C: fp32 vector fallback (correct, ~3 ms) ----
    float* xn   = (float*)d_ws;
    float* qkv  = xn + (size_t)NM * NDIM;
    float* aout = qkv + (size_t)NM * NQKV;

    rmsnorm_k<1><<<NM, 256, 0, stream>>>(x, sc, nullptr, nullptr, xn);
    gemm_f32_k<0><<<dim3(NQKV / FBM, NM / FBM), 256, 0, stream>>>(
        xn, wq, wk, wv, fc, fs, nullptr, qkv);
    attn_k<1><<<dim3(NS / BQ, NB * NH), 256, 0, stream>>>(qkv, nullptr, nullptr, aout);
    gemm_f32_k<1><<<dim3(NDIM / FBM, NM / FBM), 256, 0, stream>>>(
        aout, wo, nullptr, nullptr, nullptr, nullptr, xn, out);
  } else {
    // ---- PATH D: ws too small for any correct path. Clean wrong-answer,
    // zero OOB writes (diagnostic: tells us ws_size < 117.4 MB). ----
    zerofill_k<<<2048, 256, 0, stream>>>(out, (long long)out_size);
  }
}

// Round 6
// 1060.354 us; speedup vs baseline: 1.8223x; 1.8223x over previous
//
#include <hip/hip_runtime.h>
#include <math.h>

// (B,S,DIM,H,KVH) = (2,1024,4096,32,8)
#define NB    2
#define NS    1024
#define NDIM  4096
#define NH    32
#define NKVH  8
#define NHD   128
#define NKVD  1024
#define NM    (NB*NS)            // 2048 rows
#define NQKV  (NDIM + 2*NKVD)    // 6144

typedef __attribute__((ext_vector_type(8))) short bf16x8;
typedef __attribute__((ext_vector_type(4))) float f32x4;

#define AS3(p) ((__attribute__((address_space(3))) void*)(p))
#define AS1(p) ((const __attribute__((address_space(1))) void*)(p))

__device__ __forceinline__ unsigned short f2bf(float f) {
  unsigned u = __builtin_bit_cast(unsigned, f);
  u += 0x7fffu + ((u >> 16) & 1u);
  return (unsigned short)(u >> 16);
}
__device__ __forceinline__ float bf2f(unsigned short h) {
  unsigned u = ((unsigned)h) << 16;
  return __builtin_bit_cast(float, u);
}
// v ~= hi + lo, ~16 mantissa bits total -> split-GEMM rel err ~1e-5
__device__ __forceinline__ void split2(float v, unsigned short& h, unsigned short& l) {
  h = f2bf(v);
  l = f2bf(v - bf2f(h));
}
__device__ __forceinline__ void split8(const float* f, bf16x8& h, bf16x8& l) {
#pragma unroll
  for (int i = 0; i < 8; ++i) {
    unsigned short hh, ll;
    split2(f[i], hh, ll);
    h[i] = (short)hh; l[i] = (short)ll;
  }
}

// ---------------------------------------------------------------------------
// RMSNorm. OFMT 0: split bf16 hi/lo. OFMT 1: f32. One block per row.
// ---------------------------------------------------------------------------
template <int OFMT>
__global__ __launch_bounds__(256) void rmsnorm_k(const float* __restrict__ x,
                                                 const float* __restrict__ scale,
                                                 unsigned short* __restrict__ xnh,
                                                 unsigned short* __restrict__ xnl,
                                                 float* __restrict__ xnf) {
  const int row = blockIdx.x;
  const float4* xr = (const float4*)(x + (size_t)row * NDIM);
  const float4* sc4 = (const float4*)scale;
  const int t = threadIdx.x;
  float4 v[4];
  float ss = 0.f;
#pragma unroll
  for (int i = 0; i < 4; ++i) {
    v[i] = xr[t + 256 * i];
    ss += v[i].x * v[i].x + v[i].y * v[i].y + v[i].z * v[i].z + v[i].w * v[i].w;
  }
#pragma unroll
  for (int m = 32; m >= 1; m >>= 1) ss += __shfl_xor(ss, m, 64);
  __shared__ float red[4];
  if ((t & 63) == 0) red[t >> 6] = ss;
  __syncthreads();
  const float r = rsqrtf((red[0] + red[1] + red[2] + red[3]) * (1.0f / NDIM) + 1e-8f);
#pragma unroll
  for (int i = 0; i < 4; ++i) {
    const float4 s4 = sc4[t + 256 * i];
    float o[4] = {v[i].x * r * s4.x, v[i].y * r * s4.y, v[i].z * r * s4.z, v[i].w * r * s4.w};
    if (OFMT == 0) {
      ushort4 h4, l4;
      split2(o[0], h4.x, l4.x); split2(o[1], h4.y, l4.y);
      split2(o[2], h4.z, l4.z); split2(o[3], h4.w, l4.w);
      *(ushort4*)&xnh[(size_t)row * NDIM + (t + 256 * i) * 4] = h4;
      *(ushort4*)&xnl[(size_t)row * NDIM + (t + 256 * i) * 4] = l4;
    } else {
      *(float4*)&xnf[(size_t)row * NDIM + (t + 256 * i) * 4] =
          make_float4(o[0], o[1], o[2], o[3]);
    }
  }
}

// ---------------------------------------------------------------------------
// fp32 -> split bf16 flat (weights). count4 = elements/4.
// ---------------------------------------------------------------------------
__global__ __launch_bounds__(256) void splitw_k(const float* __restrict__ src,
                                                unsigned short* __restrict__ dh,
                                                unsigned short* __restrict__ dl,
                                                long long count4) {
  const long long stride = (long long)gridDim.x * 256;
  for (long long i = blockIdx.x * 256LL + threadIdx.x; i < count4; i += stride) {
    const float4 v = ((const float4*)src)[i];
    ushort4 h4, l4;
    split2(v.x, h4.x, l4.x); split2(v.y, h4.y, l4.y);
    split2(v.z, h4.z, l4.z); split2(v.w, h4.w, l4.w);
    ((ushort4*)dh)[i] = h4;
    ((ushort4*)dl)[i] = l4;
  }
}

__global__ __launch_bounds__(256) void zerofill_k(float* __restrict__ p, long long n) {
  const long long stride = (long long)gridDim.x * 256;
  for (long long i = blockIdx.x * 256LL + threadIdx.x; i < n; i += stride) p[i] = 0.f;
}

// ---------------------------------------------------------------------------
// Split-bf16 MFMA GEMM (verified passing R5). C[m,n] = sum_k A[m,k]*W[n,k].
// ---------------------------------------------------------------------------
template <int EPI>
__global__ __launch_bounds__(256) void gemm_split_k(
    const unsigned short* __restrict__ Ah, const unsigned short* __restrict__ Al,
    const unsigned short* __restrict__ Bh, const unsigned short* __restrict__ Bl,
    const float* __restrict__ fc, const float* __restrict__ fs,
    const unsigned short* __restrict__ resh, const unsigned short* __restrict__ resl,
    float* __restrict__ C, int ncol0) {
  constexpr int OW = (EPI == 0) ? NQKV : NDIM;
  __shared__ unsigned short lds[4][4096];  // Ah | Al | Bh | Bl tiles [128][32]

  const int t = threadIdx.x;
  const int wave = t >> 6, lane = t & 63;
  const int wr = wave >> 1, wc = wave & 1;
  const int m0 = blockIdx.x * 128;
  const int n0 = blockIdx.y * 128;

  const int srow = t >> 2;                             // 0..63
  const int ke = (((t & 3) ^ ((srow >> 1) & 3)) * 8);  // swizzled k-elem offset
  const size_t arow0 = (size_t)(m0 + srow) * NDIM + ke;
  const size_t arow1 = (size_t)(m0 + 64 + srow) * NDIM + ke;
  const size_t brow0 = (size_t)(n0 + srow) * NDIM + ke;
  const size_t brow1 = (size_t)(n0 + 64 + srow) * NDIM + ke;
  const int ldsoff0 = wave * 512;
  const int ldsoff1 = 2048 + wave * 512;

  f32x4 acc[4][4];
#pragma unroll
  for (int i = 0; i < 4; ++i)
#pragma unroll
    for (int j = 0; j < 4; ++j) acc[i][j] = (f32x4){0.f, 0.f, 0.f, 0.f};

  const int fl = lane & 15;
  const int fq = lane >> 4;

  for (int k0 = 0; k0 < NDIM; k0 += 32) {
    __syncthreads();
    __builtin_amdgcn_global_load_lds(AS1(Ah + arow0 + k0), AS3(&lds[0][ldsoff0]), 16, 0, 0);
    __builtin_amdgcn_global_load_lds(AS1(Ah + arow1 + k0), AS3(&lds[0][ldsoff1]), 16, 0, 0);
    __builtin_amdgcn_global_load_lds(AS1(Al + arow0 + k0), AS3(&lds[1][ldsoff0]), 16, 0, 0);
    __builtin_amdgcn_global_load_lds(AS1(Al + arow1 + k0), AS3(&lds[1][ldsoff1]), 16, 0, 0);
    __builtin_amdgcn_global_load_lds(AS1(Bh + brow0 + k0), AS3(&lds[2][ldsoff0]), 16, 0, 0);
    __builtin_amdgcn_global_load_lds(AS1(Bh + brow1 + k0), AS3(&lds[2][ldsoff1]), 16, 0, 0);
    __builtin_amdgcn_global_load_lds(AS1(Bl + brow0 + k0), AS3(&lds[3][ldsoff0]), 16, 0, 0);
    __builtin_amdgcn_global_load_lds(AS1(Bl + brow1 + k0), AS3(&lds[3][ldsoff1]), 16, 0, 0);
    __syncthreads();

    bf16x8 fah[4], fal[4], fbh[4], fbl[4];
#pragma unroll
    for (int m = 0; m < 4; ++m) {
      const int r = wr * 64 + m * 16 + fl;
      const int idx = r * 32 + ((fq ^ ((r >> 1) & 3)) * 8);
      fah[m] = *(const bf16x8*)&lds[0][idx];
      fal[m] = *(const bf16x8*)&lds[1][idx];
    }
#pragma unroll
    for (int n = 0; n < 4; ++n) {
      const int r = wc * 64 + n * 16 + fl;
      const int idx = r * 32 + ((fq ^ ((r >> 1) & 3)) * 8);
      fbh[n] = *(const bf16x8*)&lds[2][idx];
      fbl[n] = *(const bf16x8*)&lds[3][idx];
    }
#pragma unroll
    for (int m = 0; m < 4; ++m)
#pragma unroll
      for (int n = 0; n < 4; ++n) {
        acc[m][n] = __builtin_amdgcn_mfma_f32_16x16x32_bf16(fah[m], fbh[n], acc[m][n], 0, 0, 0);
        acc[m][n] = __builtin_amdgcn_mfma_f32_16x16x32_bf16(fah[m], fbl[n], acc[m][n], 0, 0, 0);
        acc[m][n] = __builtin_amdgcn_mfma_f32_16x16x32_bf16(fal[m], fbh[n], acc[m][n], 0, 0, 0);
      }
  }

  if (EPI == 0) {
    const int nabs0 = ncol0 + n0;
    const bool rope = (nabs0 < NDIM + NKVD);
    const float qs = (nabs0 < NDIM) ? 0.08838834764831845f : 1.0f;
#pragma unroll
    for (int m = 0; m < 4; ++m)
#pragma unroll
      for (int j = 0; j < 4; ++j) {
        const int gm = m0 + wr * 64 + m * 16 + fq * 4 + j;
        const int si = gm & (NS - 1);
        const float c = fc[si], s = fs[si];
#pragma unroll
        for (int n = 0; n < 4; ++n) {
          const int gn = nabs0 + wc * 64 + n * 16 + fl;
          const float val = acc[m][n][j];
          float o;
          if (rope) {
            const float par = __shfl_xor(val, 1, 64);  // partner col gn^1
            o = ((gn & 1) ? (val * c + par * s) : (val * c - par * s)) * qs;
          } else {
            o = val;
          }
          C[(size_t)gm * OW + gn] = o;
        }
      }
  } else {
#pragma unroll
    for (int m = 0; m < 4; ++m)
#pragma unroll
      for (int j = 0; j < 4; ++j) {
        const int gm = m0 + wr * 64 + m * 16 + fq * 4 + j;
#pragma unroll
        for (int n = 0; n < 4; ++n) {
          const int gn = n0 + wc * 64 + n * 16 + fl;
          const size_t ri = (size_t)gm * NDIM + gn;
          C[ri] = acc[m][n][j] + bf2f(resh[ri]) + bf2f(resl[ri]);
        }
      }
  }
}

// ---------------------------------------------------------------------------
// Split-bf16 MFMA flash attention. Block = 256 thr = 4 waves, BQ=64 (wave
// owns 16 q-rows, Q hi/lo in regs), BKV=32. GQA kvh = h%8 (jnp.tile).
// Q pre-scaled by 1/sqrt(128) and RoPE'd by gemm<0>.
// LDS (40KB, XOR-16B-slot swizzled; all hot reads ds_read_b128, ~2-way max):
//   K_hi [32][128]bf16 @0     (slot16' = (d>>3) ^ (r&7))
//   K_lo            @8192
//   Vt_hi [128][32]bf16 @16384 (slot' = (kv>>3) ^ (d&3))
//   Vt_lo           @24576
//   P    [64][32]f32 @32768   (slot' = (kv>>2) ^ (q&7))
// Per kv-tile: stage K+Vt (reg-split) | QK^T (2 ntiles x 4 c x 3 mfma)
// | mask | online softmax (16-lane shfl groups) | P->LDS | PV (8 dt x 3 mfma).
// C/D map: col=lane&15, row=(lane>>4)*4+j (HW-verified by gemm_split_k pass).
// ---------------------------------------------------------------------------
__global__ __launch_bounds__(256) void attn_mfma_k(const float* __restrict__ qkv,
                                                   unsigned short* __restrict__ aoh,
                                                   unsigned short* __restrict__ aol) {
  const int qt = (NS / 64 - 1) - blockIdx.x;  // heavy-first
  const int bh = blockIdx.y;
  const int b = bh >> 5;
  const int h = bh & 31;
  const int kvh = h & 7;
  const int q0 = qt * 64;

  __shared__ __align__(16) char ldsB[40960];

  const int t = threadIdx.x;
  const int w = t >> 6, lane = t & 63;
  const int l15 = lane & 15, lq = lane >> 4;

  // Q fragments in registers (hi/lo), rows = q0 + w*16 + l15
  bf16x8 qh[4], ql[4];
  {
    const float* qp = qkv + (size_t)(b * NS + q0 + w * 16 + l15) * NQKV + h * NHD;
#pragma unroll
    for (int c = 0; c < 4; ++c) {
      float qa[8];
      const float4 a = *(const float4*)(qp + lq * 8 + 32 * c);
      const float4 b2 = *(const float4*)(qp + lq * 8 + 32 * c + 4);
      qa[0] = a.x; qa[1] = a.y; qa[2] = a.z; qa[3] = a.w;
      qa[4] = b2.x; qa[5] = b2.y; qa[6] = b2.z; qa[7] = b2.w;
      split8(qa, qh[c], ql[c]);
    }
  }

  f32x4 o[8];
#pragma unroll
  for (int dt = 0; dt < 8; ++dt) o[dt] = (f32x4){0.f, 0.f, 0.f, 0.f};
  float m_run[4] = {-INFINITY, -INFINITY, -INFINITY, -INFINITY};
  float l_run[4] = {0.f, 0.f, 0.f, 0.f};

  const int ntiles = 2 * qt + 2;
  for (int jt = 0; jt < ntiles; ++jt) {
    const int kv0 = jt * 32;
    __syncthreads();  // prev tile's LDS reads complete before overwrite
    {  // stage K (row-major hi/lo) + Vt (transposed hi/lo). r = kv row.
      const int r = t >> 3, d0 = (t & 7) * 16;
      const float* kp = qkv + (size_t)(b * NS + kv0 + r) * NQKV + NDIM + kvh * NHD + d0;
      const float* vp = kp + NKVD;
      float kf[16], vf[16];
#pragma unroll
      for (int i = 0; i < 4; ++i) {
        const float4 k4 = *(const float4*)(kp + 4 * i);
        const float4 v4 = *(const float4*)(vp + 4 * i);
        kf[4 * i] = k4.x; kf[4 * i + 1] = k4.y; kf[4 * i + 2] = k4.z; kf[4 * i + 3] = k4.w;
        vf[4 * i] = v4.x; vf[4 * i + 1] = v4.y; vf[4 * i + 2] = v4.z; vf[4 * i + 3] = v4.w;
      }
#pragma unroll
      for (int g = 0; g < 2; ++g) {
        bf16x8 hi, lo;
        split8(kf + 8 * g, hi, lo);
        const int slotp = (((t & 7) * 2 + g) ^ (r & 7));
        *(bf16x8*)(ldsB + r * 256 + slotp * 16) = hi;
        *(bf16x8*)(ldsB + 8192 + r * 256 + slotp * 16) = lo;
      }
#pragma unroll
      for (int c = 0; c < 16; ++c) {
        const int d = d0 + c;
        unsigned short sh, sl;
        split2(vf[c], sh, sl);
        const int by = 16384 + d * 64 + (((r >> 3) ^ (d & 3)) * 16) + (r & 7) * 2;
        *(unsigned short*)(ldsB + by) = sh;
        *(unsigned short*)(ldsB + 8192 + by) = sl;
      }
    }
    __syncthreads();

    // QK^T: s0 (kv cols 0..15), s1 (16..31)
    f32x4 s0 = (f32x4){0.f, 0.f, 0.f, 0.f}, s1 = (f32x4){0.f, 0.f, 0.f, 0.f};
    {
      const char* kb = ldsB + l15 * 256;
#pragma unroll
      for (int c = 0; c < 4; ++c) {
        const int sa = ((lq + 4 * c) ^ (l15 & 7)) * 16;
        const bf16x8 k0h = *(const bf16x8*)(kb + sa);
        const bf16x8 k0l = *(const bf16x8*)(kb + 8192 + sa);
        const bf16x8 k1h = *(const bf16x8*)(kb + 4096 + sa);
        const bf16x8 k1l = *(const bf16x8*)(kb + 12288 + sa);
        s0 = __builtin_amdgcn_mfma_f32_16x16x32_bf16(qh[c], k0h, s0, 0, 0, 0);
        s0 = __builtin_amdgcn_mfma_f32_16x16x32_bf16(qh[c], k0l, s0, 0, 0, 0);
        s0 = __builtin_amdgcn_mfma_f32_16x16x32_bf16(ql[c], k0h, s0, 0, 0, 0);
        s1 = __builtin_amdgcn_mfma_f32_16x16x32_bf16(qh[c], k1h, s1, 0, 0, 0);
        s1 = __builtin_amdgcn_mfma_f32_16x16x32_bf16(qh[c], k1l, s1, 0, 0, 0);
        s1 = __builtin_amdgcn_mfma_f32_16x16x32_bf16(ql[c], k1h, s1, 0, 0, 0);
      }
    }

    // causal mask (only the last two kv-tiles can cross the diagonal)
    if (jt >= 2 * qt) {
#pragma unroll
      for (int j = 0; j < 4; ++j) {
        const int qg = q0 + w * 16 + lq * 4 + j;
        if (kv0 + l15 > qg) s0[j] = -INFINITY;
        if (kv0 + 16 + l15 > qg) s1[j] = -INFINITY;
      }
    }

    // online softmax per q-row (rows live in 16-lane groups)
    float resc[4];
#pragma unroll
    for (int j = 0; j < 4; ++j) {
      float mx = fmaxf(s0[j], s1[j]);
#pragma unroll
      for (int mm = 1; mm <= 8; mm <<= 1) mx = fmaxf(mx, __shfl_xor(mx, mm, 64));
      const float mn = fmaxf(m_run[j], mx);
      resc[j] = __expf(m_run[j] - mn);
      s0[j] = __expf(s0[j] - mn);
      s1[j] = __expf(s1[j] - mn);
      float ps = s0[j] + s1[j];
#pragma unroll
      for (int mm = 1; mm <= 8; mm <<= 1) ps += __shfl_xor(ps, mm, 64);
      l_run[j] = l_run[j] * resc[j] + ps;
      m_run[j] = mn;
    }
    // write P to LDS (f32, swizzled); rescale O
#pragma unroll
    for (int j = 0; j < 4; ++j) {
      const int q = w * 16 + lq * 4 + j;
      const int by0 = 32768 + q * 128 + (((l15 >> 2) ^ (q & 7)) * 16) + (l15 & 3) * 4;
      *(float*)(ldsB + by0) = s0[j];
      const int kv1 = 16 + l15;
      const int by1 = 32768 + q * 128 + (((kv1 >> 2) ^ (q & 7)) * 16) + (kv1 & 3) * 4;
      *(float*)(ldsB + by1) = s1[j];
    }
#pragma unroll
    for (int dt = 0; dt < 8; ++dt)
#pragma unroll
      for (int j = 0; j < 4; ++j) o[dt][j] *= resc[j];
    __syncthreads();  // P visible (cross-lane)

    // PV: A-frag = P rows (q = w*16+l15, kv chunk lq*8), B-frag = Vt rows (d)
    {
      const int qrow = w * 16 + l15;
      const int byA = 32768 + qrow * 128 + (((2 * lq) ^ (qrow & 7)) * 16);
      const int byB = 32768 + qrow * 128 + (((2 * lq + 1) ^ (qrow & 7)) * 16);
      const float4 pA = *(const float4*)(ldsB + byA);
      const float4 pB = *(const float4*)(ldsB + byB);
      float pf[8] = {pA.x, pA.y, pA.z, pA.w, pB.x, pB.y, pB.z, pB.w};
      bf16x8 pah, pal;
      split8(pf, pah, pal);
#pragma unroll
      for (int dt = 0; dt < 8; ++dt) {
        const int vrow = dt * 16 + l15;
        const int bv = 16384 + vrow * 64 + ((lq ^ (vrow & 3)) * 16);
        const bf16x8 vbh = *(const bf16x8*)(ldsB + bv);
        const bf16x8 vbl = *(const bf16x8*)(ldsB + bv + 8192);
        o[dt] = __builtin_amdgcn_mfma_f32_16x16x32_bf16(pah, vbh, o[dt], 0, 0, 0);
        o[dt] = __builtin_amdgcn_mfma_f32_16x16x32_bf16(pah, vbl, o[dt], 0, 0, 0);
        o[dt] = __builtin_amdgcn_mfma_f32_16x16x32_bf16(pal, vbh, o[dt], 0, 0, 0);
      }
    }
  }

  // epilogue: O/l -> split bf16
  float invl[4];
#pragma unroll
  for (int j = 0; j < 4; ++j) invl[j] = 1.0f / l_run[j];
#pragma unroll
  for (int j = 0; j < 4; ++j) {
    const size_t row = (size_t)(b * NS + q0 + w * 16 + lq * 4 + j) * NDIM + h * NHD;
#pragma unroll
    for (int dt = 0; dt < 8; ++dt) {
      unsigned short hh, ll;
      split2(o[dt][j] * invl[j], hh, ll);
      aoh[row + dt * 16 + l15] = hh;
      aol[row + dt * 16 + l15] = ll;
    }
  }
}

// ---------------------------------------------------------------------------
// fp32 vector GEMM (PATH C fallback).
// ---------------------------------------------------------------------------
#define FBM 64
#define FBK 32
#define LPAD 68

template <int EPI>
__global__ __launch_bounds__(256) void gemm_f32_k(const float* __restrict__ A,
                                                  const float* __restrict__ Wq,
                                                  const float* __restrict__ Wk,
                                                  const float* __restrict__ Wv,
                                                  const float* __restrict__ fc,
                                                  const float* __restrict__ fs,
                                                  const float* __restrict__ resid,
                                                  float* __restrict__ C) {
  __shared__ float As[FBK][LPAD];
  __shared__ float Bs[FBK][LPAD];
  const int t = threadIdx.x;
  const int tx = t & 15, ty = t >> 4;
  const int m0 = blockIdx.y * FBM;
  const int n0 = blockIdx.x * FBM;

  const float* W;
  int wn0;
  if (EPI == 0) {
    if (n0 < NDIM)              { W = Wq; wn0 = n0; }
    else if (n0 < NDIM + NKVD)  { W = Wk; wn0 = n0 - NDIM; }
    else                        { W = Wv; wn0 = n0 - NDIM - NKVD; }
  } else {
    W = Wq; wn0 = n0;
  }

  const int srow = t >> 3;
  const int skk  = (t & 7) * 4;
  const float* Ar = A + (size_t)(m0 + srow) * NDIM + skk;
  const float* Br = W + (size_t)(wn0 + srow) * NDIM + skk;

  float acc[4][4] = {};

  for (int k0 = 0; k0 < NDIM; k0 += FBK) {
    const float4 a0 = *(const float4*)(Ar + k0);
    const float4 a1 = *(const float4*)(Ar + k0 + (size_t)32 * NDIM);
    const float4 b0 = *(const float4*)(Br + k0);
    const float4 b1 = *(const float4*)(Br + k0 + (size_t)32 * NDIM);
    __syncthreads();
    As[skk + 0][srow] = a0.x; As[skk + 1][srow] = a0.y;
    As[skk + 2][srow] = a0.z; As[skk + 3][srow] = a0.w;
    As[skk + 0][srow + 32] = a1.x; As[skk + 1][srow + 32] = a1.y;
    As[skk + 2][srow + 32] = a1.z; As[skk + 3][srow + 32] = a1.w;
    Bs[skk + 0][srow] = b0.x; Bs[skk + 1][srow] = b0.y;
    Bs[skk + 2][srow] = b0.z; Bs[skk + 3][srow] = b0.w;
    Bs[skk + 0][srow + 32] = b1.x; Bs[skk + 1][srow + 32] = b1.y;
    Bs[skk + 2][srow + 32] = b1.z; Bs[skk + 3][srow + 32] = b1.w;
    __syncthreads();
#pragma unroll
    for (int k = 0; k < FBK; ++k) {
      const float4 a = *(const float4*)&As[k][ty * 4];
      const float4 b = *(const float4*)&Bs[k][tx * 4];
      const float av[4] = {a.x, a.y, a.z, a.w};
      const float bv[4] = {b.x, b.y, b.z, b.w};
#pragma unroll
      for (int i = 0; i < 4; ++i)
#pragma unroll
        for (int j = 0; j < 4; ++j)
          acc[i][j] = fmaf(av[i], bv[j], acc[i][j]);
    }
  }

  if (EPI == 0) {
    const bool rope = (n0 < NDIM + NKVD);
    const float qs = (n0 < NDIM) ? 0.08838834764831845f : 1.0f;
#pragma unroll
    for (int i = 0; i < 4; ++i) {
      const int m = m0 + ty * 4 + i;
      const int s = m & (NS - 1);
      const float c = fc[s], sn = fs[s];
      float4 o;
      if (rope) {
        o.x = (acc[i][0] * c - acc[i][1] * sn) * qs;
        o.y = (acc[i][0] * sn + acc[i][1] * c) * qs;
        o.z = (acc[i][2] * c - acc[i][3] * sn) * qs;
        o.w = (acc[i][2] * sn + acc[i][3] * c) * qs;
      } else {
        o = make_float4(acc[i][0], acc[i][1], acc[i][2], acc[i][3]);
      }
      *(float4*)(C + (size_t)m * NQKV + n0 + tx * 4) = o;
    }
  } else {
#pragma unroll
    for (int i = 0; i < 4; ++i) {
      const int m = m0 + ty * 4 + i;
      const float4 r4 = *(const float4*)(resid + (size_t)m * NDIM + n0 + tx * 4);
      *(float4*)(C + (size_t)m * NDIM + n0 + tx * 4) =
          make_float4(acc[i][0] + r4.x, acc[i][1] + r4.y, acc[i][2] + r4.z, acc[i][3] + r4.w);
    }
  }
}

// ---------------------------------------------------------------------------
// fp32 VALU flash attention (PATH C fallback only).
// ---------------------------------------------------------------------------
#define BQ 32
#define BKV 32
#define KPAD 132

__global__ __launch_bounds__(256) void attn_f32_k(const float* __restrict__ qkv,
                                                  float* __restrict__ aof) {
  const int qt = blockIdx.x;
  const int bh = blockIdx.y;
  const int b = bh >> 5;
  const int h = bh & 31;
  const int kvh = h & 7;

  __shared__ float Qs[BQ][KPAD];
  __shared__ float Ks[BKV][KPAD];
  __shared__ float Vs[BKV][KPAD];
  __shared__ float Ps[BQ][BKV + 1];

  const int t = threadIdx.x;
  const int lane8 = t & 7;
  const int qi = t >> 3;
  const int q0 = qt * BQ;

  {
    const float* qrow = qkv + (size_t)(b * NS + q0 + qi) * NQKV + h * NHD + lane8 * 16;
#pragma unroll
    for (int i = 0; i < 4; ++i)
      *(float4*)&Qs[qi][lane8 * 16 + 4 * i] = *(const float4*)(qrow + 4 * i);
  }

  float m_run = -INFINITY, l_run = 0.f;
  float4 o0 = {0,0,0,0}, o1 = {0,0,0,0}, o2 = {0,0,0,0}, o3 = {0,0,0,0};

  const size_t kbase = (size_t)(b * NS) * NQKV + NDIM + (size_t)kvh * NHD;
  const size_t vbase = kbase + NKVD;

  for (int jt = 0; jt <= qt; ++jt) {
    const int kv0 = jt * BKV;
    const float* kr = qkv + kbase + (size_t)(kv0 + qi) * NQKV + lane8 * 16;
    const float* vr = qkv + vbase + (size_t)(kv0 + qi) * NQKV + lane8 * 16;
    __syncthreads();
#pragma unroll
    for (int i = 0; i < 4; ++i) {
      *(float4*)&Ks[qi][lane8 * 16 + 4 * i] = *(const float4*)(kr + 4 * i);
      *(float4*)&Vs[qi][lane8 * 16 + 4 * i] = *(const float4*)(vr + 4 * i);
    }
    __syncthreads();

    float scv[4] = {0.f, 0.f, 0.f, 0.f};
#pragma unroll
    for (int d4 = 0; d4 < NHD / 4; ++d4) {
      const float4 q4 = *(const float4*)&Qs[qi][4 * d4];
#pragma unroll
      for (int j = 0; j < 4; ++j) {
        const float4 k4 = *(const float4*)&Ks[lane8 + 8 * j][4 * d4];
        scv[j] = fmaf(q4.x, k4.x, fmaf(q4.y, k4.y, fmaf(q4.z, k4.z, fmaf(q4.w, k4.w, scv[j]))));
      }
    }
    if (jt == qt) {
#pragma unroll
      for (int j = 0; j < 4; ++j)
        if (lane8 + 8 * j > qi) scv[j] = -INFINITY;
    }

    float mloc = fmaxf(fmaxf(scv[0], scv[1]), fmaxf(scv[2], scv[3]));
#pragma unroll
    for (int mm = 1; mm <= 4; mm <<= 1) mloc = fmaxf(mloc, __shfl_xor(mloc, mm, 64));
    const float m_new = fmaxf(m_run, mloc);
    const float resc = __expf(m_run - m_new);
    float p[4], psum = 0.f;
#pragma unroll
    for (int j = 0; j < 4; ++j) { p[j] = __expf(scv[j] - m_new); psum += p[j]; }
#pragma unroll
    for (int mm = 1; mm <= 4; mm <<= 1) psum += __shfl_xor(psum, mm, 64);
    l_run = l_run * resc + psum;
    m_run = m_new;
    o0.x *= resc; o0.y *= resc; o0.z *= resc; o0.w *= resc;
    o1.x *= resc; o1.y *= resc; o1.z *= resc; o1.w *= resc;
    o2.x *= resc; o2.y *= resc; o2.z *= resc; o2.w *= resc;
    o3.x *= resc; o3.y *= resc; o3.z *= resc; o3.w *= resc;
#pragma unroll
    for (int j = 0; j < 4; ++j) Ps[qi][lane8 + 8 * j] = p[j];
    __syncthreads();

#pragma unroll
    for (int kk = 0; kk < BKV; ++kk) {
      const float pv = Ps[qi][kk];
      const float4 v0 = *(const float4*)&Vs[kk][lane8 * 4];
      const float4 v1 = *(const float4*)&Vs[kk][lane8 * 4 + 32];
      const float4 v2 = *(const float4*)&Vs[kk][lane8 * 4 + 64];
      const float4 v3 = *(const float4*)&Vs[kk][lane8 * 4 + 96];
      o0.x = fmaf(pv, v0.x, o0.x); o0.y = fmaf(pv, v0.y, o0.y);
      o0.z = fmaf(pv, v0.z, o0.z); o0.w = fmaf(pv, v0.w, o0.w);
      o1.x = fmaf(pv, v1.x, o1.x); o1.y = fmaf(pv, v1.y, o1.y);
      o1.z = fmaf(pv, v1.z, o1.z); o1.w = fmaf(pv, v1.w, o1.w);
      o2.x = fmaf(pv, v2.x, o2.x); o2.y = fmaf(pv, v2.y, o2.y);
      o2.z = fmaf(pv, v2.z, o2.z); o2.w = fmaf(pv, v2.w, o2.w);
      o3.x = fmaf(pv, v3.x, o3.x); o3.y = fmaf(pv, v3.y, o3.y);
      o3.z = fmaf(pv, v3.z, o3.z); o3.w = fmaf(pv, v3.w, o3.w);
    }
  }

  const float inv_l = 1.0f / l_run;
  const size_t rowb = (size_t)(b * NS + q0 + qi) * NDIM + h * NHD;
  *(float4*)&aof[rowb + lane8 * 4]      = make_float4(o0.x*inv_l, o0.y*inv_l, o0.z*inv_l, o0.w*inv_l);
  *(float4*)&aof[rowb + lane8 * 4 + 32] = make_float4(o1.x*inv_l, o1.y*inv_l, o1.z*inv_l, o1.w*inv_l);
  *(float4*)&aof[rowb + lane8 * 4 + 64] = make_float4(o2.x*inv_l, o2.y*inv_l, o2.z*inv_l, o2.w*inv_l);
  *(float4*)&aof[rowb + lane8 * 4 + 96] = make_float4(o3.x*inv_l, o3.y*inv_l, o3.z*inv_l, o3.w*inv_l);
}

// ---------------------------------------------------------------------------
extern "C" void kernel_launch(void* const* d_in, const int* in_sizes, int n_in,
                              void* d_out, int out_size, void* d_ws, size_t ws_size,
                              hipStream_t stream) {
  const float* x  = (const float*)d_in[0];
  const float* sc = (const float*)d_in[1];
  const float* wq = (const float*)d_in[2];
  const float* wk = (const float*)d_in[3];
  const float* wv = (const float*)d_in[4];
  const float* wo = (const float*)d_in[5];
  const float* fc = (const float*)d_in[6];
  const float* fs = (const float*)d_in[7];
  float* out = (float*)d_out;

  const size_t bf = (size_t)NM * NDIM * 2;          // 16.78 MB (one bf16 plane)
  const size_t qkvB = (size_t)NM * NQKV * 4;        // 50.33 MB
  const size_t needA = 4 * bf + qkvB + (size_t)NQKV * NDIM * 4;  // 218.10 MB
  const size_t needB = 4 * bf + qkvB + (size_t)NDIM * NDIM * 4;  // 184.55 MB
  const size_t needC = 2 * (size_t)NM * NDIM * 4 + qkvB;         // 117.44 MB

  if (ws_size >= needB) {
    unsigned short* xnh = (unsigned short*)d_ws;
    unsigned short* xnl = xnh + (size_t)NM * NDIM;
    float* qkv = (float*)(xnl + (size_t)NM * NDIM);
    unsigned short* aoh = (unsigned short*)(qkv + (size_t)NM * NQKV);
    unsigned short* aol = aoh + (size_t)NM * NDIM;
    unsigned short* wh  = aol + (size_t)NM * NDIM;

    rmsnorm_k<0><<<NM, 256, 0, stream>>>(x, sc, xnh, xnl, nullptr);

    if (ws_size >= needA) {  // PATH A: fused QKV weight split
      unsigned short* wl = wh + (size_t)NQKV * NDIM;
      splitw_k<<<1024, 256, 0, stream>>>(wq, wh, wl, (long long)NDIM * NDIM / 4);
      splitw_k<<<1024, 256, 0, stream>>>(wk, wh + (size_t)NDIM * NDIM,
                                         wl + (size_t)NDIM * NDIM, (long long)NKVD * NDIM / 4);
      splitw_k<<<1024, 256, 0, stream>>>(wv, wh + (size_t)(NDIM + NKVD) * NDIM,
                                         wl + (size_t)(NDIM + NKVD) * NDIM,
                                         (long long)NKVD * NDIM / 4);
      gemm_split_k<0><<<dim3(NM / 128, NQKV / 128), 256, 0, stream>>>(
          xnh, xnl, wh, wl, fc, fs, nullptr, nullptr, qkv, 0);
      attn_mfma_k<<<dim3(NS / 64, NB * NH), 256, 0, stream>>>(qkv, aoh, aol);
      splitw_k<<<1024, 256, 0, stream>>>(wo, wh, wl, (long long)NDIM * NDIM / 4);
      gemm_split_k<1><<<dim3(NM / 128, NDIM / 128), 256, 0, stream>>>(
          aoh, aol, wh, wl, nullptr, nullptr, xnh, xnl, out, 0);
    } else {  // PATH B: sequenced weight buffer
      unsigned short* wl = wh + (size_t)NDIM * NDIM;
      splitw_k<<<1024, 256, 0, stream>>>(wq, wh, wl, (long long)NDIM * NDIM / 4);
      gemm_split_k<0><<<dim3(NM / 128, NDIM / 128), 256, 0, stream>>>(
          xnh, xnl, wh, wl, fc, fs, nullptr, nullptr, qkv, 0);
      splitw_k<<<1024, 256, 0, stream>>>(wk, wh, wl, (long long)NKVD * NDIM / 4);
      splitw_k<<<1024, 256, 0, stream>>>(wv, wh + (size_t)NKVD * NDIM,
                                         wl + (size_t)NKVD * NDIM, (long long)NKVD * NDIM / 4);
      gemm_split_k<0><<<dim3(NM / 128, (2 * NKVD) / 128), 256, 0, stream>>>(
          xnh, xnl, wh, wl, fc, fs, nullptr, nullptr, qkv, NDIM);
      attn_mfma_k<<<dim3(NS / 64, NB * NH), 256, 0, stream>>>(qkv, aoh, aol);
      splitw_k<<<1024, 256, 0, stream>>>(wo, wh, wl, (long long)NDIM * NDIM / 4);
      gemm_split_k<1><<<dim3(NM / 128, NDIM / 128), 256, 0, stream>>>(
          aoh, aol, wh, wl, nullptr, nullptr, xnh, xnl, out, 0);
    }
  } else if (ws_size >= needC) {
    // PATH C: fp32 vector fallback
    float* xn   = (float*)d_ws;
    float* qkv  = xn + (size_t)NM * NDIM;
    float* aout = qkv + (size_t)NM * NQKV;

    rmsnorm_k<1><<<NM, 256, 0, stream>>>(x, sc, nullptr, nullptr, xn);
    gemm_f32_k<0><<<dim3(NQKV / FBM, NM / FBM), 256, 0, stream>>>(
        xn, wq, wk, wv, fc, fs, nullptr, qkv);
    attn_f32_k<<<dim3(NS / BQ, NB * NH), 256, 0, stream>>>(qkv, aout);
    gemm_f32_k<1><<<dim3(NDIM / FBM, NM / FBM), 256, 0, stream>>>(
        aout, wo, nullptr, nullptr, nullptr, nullptr, xn, out);
  } else {
    // PATH D: diagnostic clean-fail
    zerofill_k<<<2048, 256, 0, stream>>>(out, (long long)out_size);
  }
}

// Round 7
// 941.145 us; speedup vs baseline: 2.0531x; 1.1267x over previous
//
#include <hip/hip_runtime.h>
#include <math.h>

// (B,S,DIM,H,KVH) = (2,1024,4096,32,8)
#define NB    2
#define NS    1024
#define NDIM  4096
#define NH    32
#define NKVH  8
#define NHD   128
#define NKVD  1024
#define NM    (NB*NS)            // 2048 rows
#define NQKV  (NDIM + 2*NKVD)    // 6144

typedef __attribute__((ext_vector_type(8))) short bf16x8;
typedef __attribute__((ext_vector_type(4))) float f32x4;

#define AS3(p) ((__attribute__((address_space(3))) void*)(p))
#define AS1(p) ((const __attribute__((address_space(1))) void*)(p))

__device__ __forceinline__ unsigned short f2bf(float f) {
  unsigned u = __builtin_bit_cast(unsigned, f);
  u += 0x7fffu + ((u >> 16) & 1u);
  return (unsigned short)(u >> 16);
}
__device__ __forceinline__ float bf2f(unsigned short h) {
  unsigned u = ((unsigned)h) << 16;
  return __builtin_bit_cast(float, u);
}
// v ~= hi + lo, ~16 mantissa bits total -> split-GEMM rel err ~1e-5
__device__ __forceinline__ void split2(float v, unsigned short& h, unsigned short& l) {
  h = f2bf(v);
  l = f2bf(v - bf2f(h));
}
__device__ __forceinline__ void split8(const float* f, bf16x8& h, bf16x8& l) {
#pragma unroll
  for (int i = 0; i < 8; ++i) {
    unsigned short hh, ll;
    split2(f[i], hh, ll);
    h[i] = (short)hh; l[i] = (short)ll;
  }
}

// ---------------------------------------------------------------------------
// RMSNorm. OFMT 0: split bf16 hi/lo. OFMT 1: f32. One block per row.
// ---------------------------------------------------------------------------
template <int OFMT>
__global__ __launch_bounds__(256) void rmsnorm_k(const float* __restrict__ x,
                                                 const float* __restrict__ scale,
                                                 unsigned short* __restrict__ xnh,
                                                 unsigned short* __restrict__ xnl,
                                                 float* __restrict__ xnf) {
  const int row = blockIdx.x;
  const float4* xr = (const float4*)(x + (size_t)row * NDIM);
  const float4* sc4 = (const float4*)scale;
  const int t = threadIdx.x;
  float4 v[4];
  float ss = 0.f;
#pragma unroll
  for (int i = 0; i < 4; ++i) {
    v[i] = xr[t + 256 * i];
    ss += v[i].x * v[i].x + v[i].y * v[i].y + v[i].z * v[i].z + v[i].w * v[i].w;
  }
#pragma unroll
  for (int m = 32; m >= 1; m >>= 1) ss += __shfl_xor(ss, m, 64);
  __shared__ float red[4];
  if ((t & 63) == 0) red[t >> 6] = ss;
  __syncthreads();
  const float r = rsqrtf((red[0] + red[1] + red[2] + red[3]) * (1.0f / NDIM) + 1e-8f);
#pragma unroll
  for (int i = 0; i < 4; ++i) {
    const float4 s4 = sc4[t + 256 * i];
    float o[4] = {v[i].x * r * s4.x, v[i].y * r * s4.y, v[i].z * r * s4.z, v[i].w * r * s4.w};
    if (OFMT == 0) {
      ushort4 h4, l4;
      split2(o[0], h4.x, l4.x); split2(o[1], h4.y, l4.y);
      split2(o[2], h4.z, l4.z); split2(o[3], h4.w, l4.w);
      *(ushort4*)&xnh[(size_t)row * NDIM + (t + 256 * i) * 4] = h4;
      *(ushort4*)&xnl[(size_t)row * NDIM + (t + 256 * i) * 4] = l4;
    } else {
      *(float4*)&xnf[(size_t)row * NDIM + (t + 256 * i) * 4] =
          make_float4(o[0], o[1], o[2], o[3]);
    }
  }
}

// ---------------------------------------------------------------------------
// fp32 -> split bf16 flat (weights). count4 = elements/4.
// ---------------------------------------------------------------------------
__global__ __launch_bounds__(256) void splitw_k(const float* __restrict__ src,
                                                unsigned short* __restrict__ dh,
                                                unsigned short* __restrict__ dl,
                                                long long count4) {
  const long long stride = (long long)gridDim.x * 256;
  for (long long i = blockIdx.x * 256LL + threadIdx.x; i < count4; i += stride) {
    const float4 v = ((const float4*)src)[i];
    ushort4 h4, l4;
    split2(v.x, h4.x, l4.x); split2(v.y, h4.y, l4.y);
    split2(v.z, h4.z, l4.z); split2(v.w, h4.w, l4.w);
    ((ushort4*)dh)[i] = h4;
    ((ushort4*)dl)[i] = l4;
  }
}

__global__ __launch_bounds__(256) void zerofill_k(float* __restrict__ p, long long n) {
  const long long stride = (long long)gridDim.x * 256;
  for (long long i = blockIdx.x * 256LL + threadIdx.x; i < n; i += stride) p[i] = 0.f;
}

// ---------------------------------------------------------------------------
// Split-bf16 MFMA GEMM (core verified R5/R6). C[m,n] = sum_k A[m,k]*W[n,k].
// EPI 0: writes split-bf16 planes directly:
//   Q (nabs<4096):  RoPE + 1/sqrt(128) -> Qh/Ql [NM][NDIM]
//   K (4096..5119): RoPE              -> Kh/Kl [NM][NKVD]
//   V (5120..6143): transposed        -> VTh/VTl [NKVD][NM]
// EPI 1: C = acc + resid(hi+lo), f32.
// ---------------------------------------------------------------------------
template <int EPI>
__global__ __launch_bounds__(256) void gemm_split_k(
    const unsigned short* __restrict__ Ah, const unsigned short* __restrict__ Al,
    const unsigned short* __restrict__ Bh, const unsigned short* __restrict__ Bl,
    const float* __restrict__ fc, const float* __restrict__ fs,
    const unsigned short* __restrict__ resh, const unsigned short* __restrict__ resl,
    float* __restrict__ C,
    unsigned short* __restrict__ Qh, unsigned short* __restrict__ Ql,
    unsigned short* __restrict__ Kh, unsigned short* __restrict__ Kl,
    unsigned short* __restrict__ VTh, unsigned short* __restrict__ VTl,
    int ncol0) {
  __shared__ unsigned short lds[4][4096];  // Ah | Al | Bh | Bl tiles [128][32]

  const int t = threadIdx.x;
  const int wave = t >> 6, lane = t & 63;
  const int wr = wave >> 1, wc = wave & 1;
  const int m0 = blockIdx.x * 128;
  const int n0 = blockIdx.y * 128;

  const int srow = t >> 2;                             // 0..63
  const int ke = (((t & 3) ^ ((srow >> 1) & 3)) * 8);  // swizzled k-elem offset
  const size_t arow0 = (size_t)(m0 + srow) * NDIM + ke;
  const size_t arow1 = (size_t)(m0 + 64 + srow) * NDIM + ke;
  const size_t brow0 = (size_t)(n0 + srow) * NDIM + ke;
  const size_t brow1 = (size_t)(n0 + 64 + srow) * NDIM + ke;
  const int ldsoff0 = wave * 512;
  const int ldsoff1 = 2048 + wave * 512;

  f32x4 acc[4][4];
#pragma unroll
  for (int i = 0; i < 4; ++i)
#pragma unroll
    for (int j = 0; j < 4; ++j) acc[i][j] = (f32x4){0.f, 0.f, 0.f, 0.f};

  const int fl = lane & 15;
  const int fq = lane >> 4;

  for (int k0 = 0; k0 < NDIM; k0 += 32) {
    __syncthreads();
    __builtin_amdgcn_global_load_lds(AS1(Ah + arow0 + k0), AS3(&lds[0][ldsoff0]), 16, 0, 0);
    __builtin_amdgcn_global_load_lds(AS1(Ah + arow1 + k0), AS3(&lds[0][ldsoff1]), 16, 0, 0);
    __builtin_amdgcn_global_load_lds(AS1(Al + arow0 + k0), AS3(&lds[1][ldsoff0]), 16, 0, 0);
    __builtin_amdgcn_global_load_lds(AS1(Al + arow1 + k0), AS3(&lds[1][ldsoff1]), 16, 0, 0);
    __builtin_amdgcn_global_load_lds(AS1(Bh + brow0 + k0), AS3(&lds[2][ldsoff0]), 16, 0, 0);
    __builtin_amdgcn_global_load_lds(AS1(Bh + brow1 + k0), AS3(&lds[2][ldsoff1]), 16, 0, 0);
    __builtin_amdgcn_global_load_lds(AS1(Bl + brow0 + k0), AS3(&lds[3][ldsoff0]), 16, 0, 0);
    __builtin_amdgcn_global_load_lds(AS1(Bl + brow1 + k0), AS3(&lds[3][ldsoff1]), 16, 0, 0);
    __syncthreads();

    bf16x8 fah[4], fal[4], fbh[4], fbl[4];
#pragma unroll
    for (int m = 0; m < 4; ++m) {
      const int r = wr * 64 + m * 16 + fl;
      const int idx = r * 32 + ((fq ^ ((r >> 1) & 3)) * 8);
      fah[m] = *(const bf16x8*)&lds[0][idx];
      fal[m] = *(const bf16x8*)&lds[1][idx];
    }
#pragma unroll
    for (int n = 0; n < 4; ++n) {
      const int r = wc * 64 + n * 16 + fl;
      const int idx = r * 32 + ((fq ^ ((r >> 1) & 3)) * 8);
      fbh[n] = *(const bf16x8*)&lds[2][idx];
      fbl[n] = *(const bf16x8*)&lds[3][idx];
    }
#pragma unroll
    for (int m = 0; m < 4; ++m)
#pragma unroll
      for (int n = 0; n < 4; ++n) {
        acc[m][n] = __builtin_amdgcn_mfma_f32_16x16x32_bf16(fah[m], fbh[n], acc[m][n], 0, 0, 0);
        acc[m][n] = __builtin_amdgcn_mfma_f32_16x16x32_bf16(fah[m], fbl[n], acc[m][n], 0, 0, 0);
        acc[m][n] = __builtin_amdgcn_mfma_f32_16x16x32_bf16(fal[m], fbh[n], acc[m][n], 0, 0, 0);
      }
  }

  // C/D map: col = lane&15 (fl), row = fq*4 + j (verified R5/R6).
  if (EPI == 0) {
    const int nabs0 = ncol0 + n0;  // block-uniform; ranges 128-aligned
    if (nabs0 < NDIM + NKVD) {
      // Q or K: RoPE (pairs = adjacent cols -> shfl_xor(1)); Q also *1/sqrt(128)
      const bool isq = (nabs0 < NDIM);
      const float qs = isq ? 0.08838834764831845f : 1.0f;
      unsigned short* dsth = isq ? Qh : Kh;
      unsigned short* dstl = isq ? Ql : Kl;
      const int colbase = isq ? nabs0 : (nabs0 - NDIM);
      const int ow = isq ? NDIM : NKVD;
#pragma unroll
      for (int m = 0; m < 4; ++m)
#pragma unroll
        for (int j = 0; j < 4; ++j) {
          const int gm = m0 + wr * 64 + m * 16 + fq * 4 + j;
          const int si = gm & (NS - 1);
          const float c = fc[si], s = fs[si];
#pragma unroll
          for (int n = 0; n < 4; ++n) {
            const int gn = colbase + wc * 64 + n * 16 + fl;
            const float val = acc[m][n][j];
            const float par = __shfl_xor(val, 1, 64);  // partner col gn^1
            const float o = ((fl & 1) ? (val * c + par * s) : (val * c - par * s)) * qs;
            unsigned short hh, ll;
            split2(o, hh, ll);
            dsth[(size_t)gm * ow + gn] = hh;
            dstl[(size_t)gm * ow + gn] = ll;
          }
        }
    } else {
      // V: write transposed VT[f][gm], pack 4 m-rows (j) per ushort4
#pragma unroll
      for (int m = 0; m < 4; ++m) {
        const int gmb = m0 + wr * 64 + m * 16 + fq * 4;
#pragma unroll
        for (int n = 0; n < 4; ++n) {
          const int f = (nabs0 - NDIM - NKVD) + wc * 64 + n * 16 + fl;
          ushort4 h4, l4;
          split2(acc[m][n][0], h4.x, l4.x);
          split2(acc[m][n][1], h4.y, l4.y);
          split2(acc[m][n][2], h4.z, l4.z);
          split2(acc[m][n][3], h4.w, l4.w);
          *(ushort4*)&VTh[(size_t)f * NM + gmb] = h4;
          *(ushort4*)&VTl[(size_t)f * NM + gmb] = l4;
        }
      }
    }
  } else {
#pragma unroll
    for (int m = 0; m < 4; ++m)
#pragma unroll
      for (int j = 0; j < 4; ++j) {
        const int gm = m0 + wr * 64 + m * 16 + fq * 4 + j;
#pragma unroll
        for (int n = 0; n < 4; ++n) {
          const int gn = n0 + wc * 64 + n * 16 + fl;
          const size_t ri = (size_t)gm * NDIM + gn;
          C[ri] = acc[m][n][j] + bf2f(resh[ri]) + bf2f(resl[ri]);
        }
      }
  }
}

// ---------------------------------------------------------------------------
// Split-bf16 MFMA flash attention v2: all K/V staging via global_load_lds DMA
// from pre-split planes (zero staging VALU). Block = 4 waves, BQ=64, BKV=32.
// GQA kvh = h%8 (jnp.tile). Q pre-RoPE'd+scaled, loaded straight to frags.
// LDS 40KB: K_hi[32][128] @0 | K_lo @8192 | VT_hi[128][32] @16384 |
//           VT_lo @24576 | P[64][32]f32 @32768.
// Swizzles (both-sides, rule #21): K slot16' = seg ^ (row&7) (2-way);
// VT slot16' = seg ^ ((d>>1)&3) (2-way); P as R6 (verified).
// ---------------------------------------------------------------------------
__global__ __launch_bounds__(256) void attn_mfma2_k(
    const unsigned short* __restrict__ Qh, const unsigned short* __restrict__ Ql,
    const unsigned short* __restrict__ Kh, const unsigned short* __restrict__ Kl,
    const unsigned short* __restrict__ VTh, const unsigned short* __restrict__ VTl,
    unsigned short* __restrict__ aoh, unsigned short* __restrict__ aol) {
  const int qt = (NS / 64 - 1) - blockIdx.x;  // heavy-first
  const int bh = blockIdx.y;
  const int b = bh >> 5;
  const int h = bh & 31;
  const int kvh = h & 7;
  const int q0 = qt * 64;

  __shared__ __align__(16) char ldsB[40960];

  const int t = threadIdx.x;
  const int w = t >> 6, lane = t & 63;
  const int l15 = lane & 15, lq = lane >> 4;

  // Q fragments straight from split planes (rows q0 + w*16 + l15)
  bf16x8 qh[4], ql[4];
  {
    const size_t qb = (size_t)(b * NS + q0 + w * 16 + l15) * NDIM + h * NHD;
#pragma unroll
    for (int c = 0; c < 4; ++c) {
      qh[c] = *(const bf16x8*)&Qh[qb + c * 32 + lq * 8];
      ql[c] = *(const bf16x8*)&Ql[qb + c * 32 + lq * 8];
    }
  }

  // staging per-thread constants (inverse-swizzled global sources)
  const int kr = t >> 4;                         // K row within 16-row issue
  const int kds = (((t & 15) ^ (kr & 7)) * 8);   // K feature offset (swz)
  const size_t kgoff = (size_t)(b * NS + kr) * NKVD + kvh * NHD + kds;
  const int vd = t >> 2;                         // VT row within 64-row issue
  const int vks = (((t & 3) ^ ((vd >> 1) & 3)) * 8);  // kv offset (swz)
  const size_t vgoff = (size_t)(kvh * NHD + vd) * NM + b * NS + vks;
  char* const kdst = ldsB + w * 1024;            // wave-uniform DMA base

  f32x4 o[8];
#pragma unroll
  for (int dt = 0; dt < 8; ++dt) o[dt] = (f32x4){0.f, 0.f, 0.f, 0.f};
  float m_run[4] = {-INFINITY, -INFINITY, -INFINITY, -INFINITY};
  float l_run[4] = {0.f, 0.f, 0.f, 0.f};

  const int ntiles = 2 * qt + 2;
  for (int jt = 0; jt < ntiles; ++jt) {
    const int kv0 = jt * 32;
    __syncthreads();  // prev tile's LDS reads complete before DMA overwrite
#pragma unroll
    for (int i = 0; i < 2; ++i) {
      const size_t kg = kgoff + (size_t)(kv0 + i * 16) * NKVD;
      const size_t vg = vgoff + kv0 + (size_t)i * 64 * NM;
      __builtin_amdgcn_global_load_lds(AS1(Kh + kg),  AS3(kdst + i * 4096), 16, 0, 0);
      __builtin_amdgcn_global_load_lds(AS1(Kl + kg),  AS3(kdst + 8192 + i * 4096), 16, 0, 0);
      __builtin_amdgcn_global_load_lds(AS1(VTh + vg), AS3(kdst + 16384 + i * 4096), 16, 0, 0);
      __builtin_amdgcn_global_load_lds(AS1(VTl + vg), AS3(kdst + 24576 + i * 4096), 16, 0, 0);
    }
    __syncthreads();  // vmcnt drained by compiler before barrier

    // QK^T: s0 (kv 0..15), s1 (16..31); B-frag rows = kv, chunks = lq+4c
    f32x4 s0 = (f32x4){0.f, 0.f, 0.f, 0.f}, s1 = (f32x4){0.f, 0.f, 0.f, 0.f};
    {
      const char* kb0 = ldsB + l15 * 256;
      const char* kb1 = ldsB + (16 + l15) * 256;
#pragma unroll
      for (int c = 0; c < 4; ++c) {
        const int sa = (((lq + 4 * c) ^ (l15 & 7)) * 16);  // (16+l15)&7 == l15&7
        const bf16x8 k0h = *(const bf16x8*)(kb0 + sa);
        const bf16x8 k0l = *(const bf16x8*)(kb0 + 8192 + sa);
        const bf16x8 k1h = *(const bf16x8*)(kb1 + sa);
        const bf16x8 k1l = *(const bf16x8*)(kb1 + 8192 + sa);
        s0 = __builtin_amdgcn_mfma_f32_16x16x32_bf16(qh[c], k0h, s0, 0, 0, 0);
        s0 = __builtin_amdgcn_mfma_f32_16x16x32_bf16(qh[c], k0l, s0, 0, 0, 0);
        s0 = __builtin_amdgcn_mfma_f32_16x16x32_bf16(ql[c], k0h, s0, 0, 0, 0);
        s1 = __builtin_amdgcn_mfma_f32_16x16x32_bf16(qh[c], k1h, s1, 0, 0, 0);
        s1 = __builtin_amdgcn_mfma_f32_16x16x32_bf16(qh[c], k1l, s1, 0, 0, 0);
        s1 = __builtin_amdgcn_mfma_f32_16x16x32_bf16(ql[c], k1h, s1, 0, 0, 0);
      }
    }

    // causal mask (last two kv-tiles only)
    if (jt >= 2 * qt) {
#pragma unroll
      for (int j = 0; j < 4; ++j) {
        const int qg = q0 + w * 16 + lq * 4 + j;
        if (kv0 + l15 > qg) s0[j] = -INFINITY;
        if (kv0 + 16 + l15 > qg) s1[j] = -INFINITY;
      }
    }

    // online softmax per q-row (16-lane groups)
    float resc[4];
#pragma unroll
    for (int j = 0; j < 4; ++j) {
      float mx = fmaxf(s0[j], s1[j]);
#pragma unroll
      for (int mm = 1; mm <= 8; mm <<= 1) mx = fmaxf(mx, __shfl_xor(mx, mm, 64));
      const float mn = fmaxf(m_run[j], mx);
      resc[j] = __expf(m_run[j] - mn);
      s0[j] = __expf(s0[j] - mn);
      s1[j] = __expf(s1[j] - mn);
      float ps = s0[j] + s1[j];
#pragma unroll
      for (int mm = 1; mm <= 8; mm <<= 1) ps += __shfl_xor(ps, mm, 64);
      l_run[j] = l_run[j] * resc[j] + ps;
      m_run[j] = mn;
    }
    // P -> LDS (f32, swizzled); rescale O
#pragma unroll
    for (int j = 0; j < 4; ++j) {
      const int q = w * 16 + lq * 4 + j;
      const int by0 = 32768 + q * 128 + (((l15 >> 2) ^ (q & 7)) * 16) + (l15 & 3) * 4;
      *(float*)(ldsB + by0) = s0[j];
      const int kv1 = 16 + l15;
      const int by1 = 32768 + q * 128 + (((kv1 >> 2) ^ (q & 7)) * 16) + (kv1 & 3) * 4;
      *(float*)(ldsB + by1) = s1[j];
    }
#pragma unroll
    for (int dt = 0; dt < 8; ++dt)
#pragma unroll
      for (int j = 0; j < 4; ++j) o[dt][j] *= resc[j];
    __syncthreads();  // P visible

    // PV: A-frag = P row (q = w*16+l15, kv chunk lq*8); B-frag = VT rows (d)
    {
      const int qrow = w * 16 + l15;
      const int byA = 32768 + qrow * 128 + (((2 * lq) ^ (qrow & 7)) * 16);
      const int byB = 32768 + qrow * 128 + (((2 * lq + 1) ^ (qrow & 7)) * 16);
      const float4 pA = *(const float4*)(ldsB + byA);
      const float4 pB = *(const float4*)(ldsB + byB);
      float pf[8] = {pA.x, pA.y, pA.z, pA.w, pB.x, pB.y, pB.z, pB.w};
      bf16x8 pah, pal;
      split8(pf, pah, pal);
#pragma unroll
      for (int dt = 0; dt < 8; ++dt) {
        const int vrow = dt * 16 + l15;
        const int bv = 16384 + vrow * 64 + ((lq ^ ((vrow >> 1) & 3)) * 16);
        const bf16x8 vbh = *(const bf16x8*)(ldsB + bv);
        const bf16x8 vbl = *(const bf16x8*)(ldsB + bv + 8192);
        o[dt] = __builtin_amdgcn_mfma_f32_16x16x32_bf16(pah, vbh, o[dt], 0, 0, 0);
        o[dt] = __builtin_amdgcn_mfma_f32_16x16x32_bf16(pah, vbl, o[dt], 0, 0, 0);
        o[dt] = __builtin_amdgcn_mfma_f32_16x16x32_bf16(pal, vbh, o[dt], 0, 0, 0);
      }
    }
  }

  // epilogue: O/l -> split bf16
  float invl[4];
#pragma unroll
  for (int j = 0; j < 4; ++j) invl[j] = 1.0f / l_run[j];
#pragma unroll
  for (int j = 0; j < 4; ++j) {
    const size_t row = (size_t)(b * NS + q0 + w * 16 + lq * 4 + j) * NDIM + h * NHD;
#pragma unroll
    for (int dt = 0; dt < 8; ++dt) {
      unsigned short hh, ll;
      split2(o[dt][j] * invl[j], hh, ll);
      aoh[row + dt * 16 + l15] = hh;
      aol[row + dt * 16 + l15] = ll;
    }
  }
}

// ---------------------------------------------------------------------------
// fp32 vector GEMM + fp32 attention (PATH C fallback, unchanged from R5).
// ---------------------------------------------------------------------------
#define FBM 64
#define FBK 32
#define LPAD 68

template <int EPI>
__global__ __launch_bounds__(256) void gemm_f32_k(const float* __restrict__ A,
                                                  const float* __restrict__ Wq,
                                                  const float* __restrict__ Wk,
                                                  const float* __restrict__ Wv,
                                                  const float* __restrict__ fc,
                                                  const float* __restrict__ fs,
                                                  const float* __restrict__ resid,
                                                  float* __restrict__ C) {
  __shared__ float As[FBK][LPAD];
  __shared__ float Bs[FBK][LPAD];
  const int t = threadIdx.x;
  const int tx = t & 15, ty = t >> 4;
  const int m0 = blockIdx.y * FBM;
  const int n0 = blockIdx.x * FBM;

  const float* W;
  int wn0;
  if (EPI == 0) {
    if (n0 < NDIM)              { W = Wq; wn0 = n0; }
    else if (n0 < NDIM + NKVD)  { W = Wk; wn0 = n0 - NDIM; }
    else                        { W = Wv; wn0 = n0 - NDIM - NKVD; }
  } else {
    W = Wq; wn0 = n0;
  }

  const int srow = t >> 3;
  const int skk  = (t & 7) * 4;
  const float* Ar = A + (size_t)(m0 + srow) * NDIM + skk;
  const float* Br = W + (size_t)(wn0 + srow) * NDIM + skk;

  float acc[4][4] = {};

  for (int k0 = 0; k0 < NDIM; k0 += FBK) {
    const float4 a0 = *(const float4*)(Ar + k0);
    const float4 a1 = *(const float4*)(Ar + k0 + (size_t)32 * NDIM);
    const float4 b0 = *(const float4*)(Br + k0);
    const float4 b1 = *(const float4*)(Br + k0 + (size_t)32 * NDIM);
    __syncthreads();
    As[skk + 0][srow] = a0.x; As[skk + 1][srow] = a0.y;
    As[skk + 2][srow] = a0.z; As[skk + 3][srow] = a0.w;
    As[skk + 0][srow + 32] = a1.x; As[skk + 1][srow + 32] = a1.y;
    As[skk + 2][srow + 32] = a1.z; As[skk + 3][srow + 32] = a1.w;
    Bs[skk + 0][srow] = b0.x; Bs[skk + 1][srow] = b0.y;
    Bs[skk + 2][srow] = b0.z; Bs[skk + 3][srow] = b0.w;
    Bs[skk + 0][srow + 32] = b1.x; Bs[skk + 1][srow + 32] = b1.y;
    Bs[skk + 2][srow + 32] = b1.z; Bs[skk + 3][srow + 32] = b1.w;
    __syncthreads();
#pragma unroll
    for (int k = 0; k < FBK; ++k) {
      const float4 a = *(const float4*)&As[k][ty * 4];
      const float4 b = *(const float4*)&Bs[k][tx * 4];
      const float av[4] = {a.x, a.y, a.z, a.w};
      const float bv[4] = {b.x, b.y, b.z, b.w};
#pragma unroll
      for (int i = 0; i < 4; ++i)
#pragma unroll
        for (int j = 0; j < 4; ++j)
          acc[i][j] = fmaf(av[i], bv[j], acc[i][j]);
    }
  }

  if (EPI == 0) {
    const bool rope = (n0 < NDIM + NKVD);
    const float qs = (n0 < NDIM) ? 0.08838834764831845f : 1.0f;
#pragma unroll
    for (int i = 0; i < 4; ++i) {
      const int m = m0 + ty * 4 + i;
      const int s = m & (NS - 1);
      const float c = fc[s], sn = fs[s];
      float4 o;
      if (rope) {
        o.x = (acc[i][0] * c - acc[i][1] * sn) * qs;
        o.y = (acc[i][0] * sn + acc[i][1] * c) * qs;
        o.z = (acc[i][2] * c - acc[i][3] * sn) * qs;
        o.w = (acc[i][2] * sn + acc[i][3] * c) * qs;
      } else {
        o = make_float4(acc[i][0], acc[i][1], acc[i][2], acc[i][3]);
      }
      *(float4*)(C + (size_t)m * NQKV + n0 + tx * 4) = o;
    }
  } else {
#pragma unroll
    for (int i = 0; i < 4; ++i) {
      const int m = m0 + ty * 4 + i;
      const float4 r4 = *(const float4*)(resid + (size_t)m * NDIM + n0 + tx * 4);
      *(float4*)(C + (size_t)m * NDIM + n0 + tx * 4) =
          make_float4(acc[i][0] + r4.x, acc[i][1] + r4.y, acc[i][2] + r4.z, acc[i][3] + r4.w);
    }
  }
}

#define BQ 32
#define BKV 32
#define KPAD 132

__global__ __launch_bounds__(256) void attn_f32_k(const float* __restrict__ qkv,
                                                  float* __restrict__ aof) {
  const int qt = blockIdx.x;
  const int bh = blockIdx.y;
  const int b = bh >> 5;
  const int h = bh & 31;
  const int kvh = h & 7;

  __shared__ float Qs[BQ][KPAD];
  __shared__ float Ks[BKV][KPAD];
  __shared__ float Vs[BKV][KPAD];
  __shared__ float Ps[BQ][BKV + 1];

  const int t = threadIdx.x;
  const int lane8 = t & 7;
  const int qi = t >> 3;
  const int q0 = qt * BQ;

  {
    const float* qrow = qkv + (size_t)(b * NS + q0 + qi) * NQKV + h * NHD + lane8 * 16;
#pragma unroll
    for (int i = 0; i < 4; ++i)
      *(float4*)&Qs[qi][lane8 * 16 + 4 * i] = *(const float4*)(qrow + 4 * i);
  }

  float m_run = -INFINITY, l_run = 0.f;
  float4 o0 = {0,0,0,0}, o1 = {0,0,0,0}, o2 = {0,0,0,0}, o3 = {0,0,0,0};

  const size_t kbase = (size_t)(b * NS) * NQKV + NDIM + (size_t)kvh * NHD;
  const size_t vbase = kbase + NKVD;

  for (int jt = 0; jt <= qt; ++jt) {
    const int kv0 = jt * BKV;
    const float* kr = qkv + kbase + (size_t)(kv0 + qi) * NQKV + lane8 * 16;
    const float* vr = qkv + vbase + (size_t)(kv0 + qi) * NQKV + lane8 * 16;
    __syncthreads();
#pragma unroll
    for (int i = 0; i < 4; ++i) {
      *(float4*)&Ks[qi][lane8 * 16 + 4 * i] = *(const float4*)(kr + 4 * i);
      *(float4*)&Vs[qi][lane8 * 16 + 4 * i] = *(const float4*)(vr + 4 * i);
    }
    __syncthreads();

    float scv[4] = {0.f, 0.f, 0.f, 0.f};
#pragma unroll
    for (int d4 = 0; d4 < NHD / 4; ++d4) {
      const float4 q4 = *(const float4*)&Qs[qi][4 * d4];
#pragma unroll
      for (int j = 0; j < 4; ++j) {
        const float4 k4 = *(const float4*)&Ks[lane8 + 8 * j][4 * d4];
        scv[j] = fmaf(q4.x, k4.x, fmaf(q4.y, k4.y, fmaf(q4.z, k4.z, fmaf(q4.w, k4.w, scv[j]))));
      }
    }
    if (jt == qt) {
#pragma unroll
      for (int j = 0; j < 4; ++j)
        if (lane8 + 8 * j > qi) scv[j] = -INFINITY;
    }

    float mloc = fmaxf(fmaxf(scv[0], scv[1]), fmaxf(scv[2], scv[3]));
#pragma unroll
    for (int mm = 1; mm <= 4; mm <<= 1) mloc = fmaxf(mloc, __shfl_xor(mloc, mm, 64));
    const float m_new = fmaxf(m_run, mloc);
    const float resc = __expf(m_run - m_new);
    float p[4], psum = 0.f;
#pragma unroll
    for (int j = 0; j < 4; ++j) { p[j] = __expf(scv[j] - m_new); psum += p[j]; }
#pragma unroll
    for (int mm = 1; mm <= 4; mm <<= 1) psum += __shfl_xor(psum, mm, 64);
    l_run = l_run * resc + psum;
    m_run = m_new;
    o0.x *= resc; o0.y *= resc; o0.z *= resc; o0.w *= resc;
    o1.x *= resc; o1.y *= resc; o1.z *= resc; o1.w *= resc;
    o2.x *= resc; o2.y *= resc; o2.z *= resc; o2.w *= resc;
    o3.x *= resc; o3.y *= resc; o3.z *= resc; o3.w *= resc;
#pragma unroll
    for (int j = 0; j < 4; ++j) Ps[qi][lane8 + 8 * j] = p[j];
    __syncthreads();

#pragma unroll
    for (int kk = 0; kk < BKV; ++kk) {
      const float pv = Ps[qi][kk];
      const float4 v0 = *(const float4*)&Vs[kk][lane8 * 4];
      const float4 v1 = *(const float4*)&Vs[kk][lane8 * 4 + 32];
      const float4 v2 = *(const float4*)&Vs[kk][lane8 * 4 + 64];
      const float4 v3 = *(const float4*)&Vs[kk][lane8 * 4 + 96];
      o0.x = fmaf(pv, v0.x, o0.x); o0.y = fmaf(pv, v0.y, o0.y);
      o0.z = fmaf(pv, v0.z, o0.z); o0.w = fmaf(pv, v0.w, o0.w);
      o1.x = fmaf(pv, v1.x, o1.x); o1.y = fmaf(pv, v1.y, o1.y);
      o1.z = fmaf(pv, v1.z, o1.z); o1.w = fmaf(pv, v1.w, o1.w);
      o2.x = fmaf(pv, v2.x, o2.x); o2.y = fmaf(pv, v2.y, o2.y);
      o2.z = fmaf(pv, v2.z, o2.z); o2.w = fmaf(pv, v2.w, o2.w);
      o3.x = fmaf(pv, v3.x, o3.x); o3.y = fmaf(pv, v3.y, o3.y);
      o3.z = fmaf(pv, v3.z, o3.z); o3.w = fmaf(pv, v3.w, o3.w);
    }
  }

  const float inv_l = 1.0f / l_run;
  const size_t rowb = (size_t)(b * NS + q0 + qi) * NDIM + h * NHD;
  *(float4*)&aof[rowb + lane8 * 4]      = make_float4(o0.x*inv_l, o0.y*inv_l, o0.z*inv_l, o0.w*inv_l);
  *(float4*)&aof[rowb + lane8 * 4 + 32] = make_float4(o1.x*inv_l, o1.y*inv_l, o1.z*inv_l, o1.w*inv_l);
  *(float4*)&aof[rowb + lane8 * 4 + 64] = make_float4(o2.x*inv_l, o2.y*inv_l, o2.z*inv_l, o2.w*inv_l);
  *(float4*)&aof[rowb + lane8 * 4 + 96] = make_float4(o3.x*inv_l, o3.y*inv_l, o3.z*inv_l, o3.w*inv_l);
}

// ---------------------------------------------------------------------------
extern "C" void kernel_launch(void* const* d_in, const int* in_sizes, int n_in,
                              void* d_out, int out_size, void* d_ws, size_t ws_size,
                              hipStream_t stream) {
  const float* x  = (const float*)d_in[0];
  const float* sc = (const float*)d_in[1];
  const float* wq = (const float*)d_in[2];
  const float* wk = (const float*)d_in[3];
  const float* wv = (const float*)d_in[4];
  const float* wo = (const float*)d_in[5];
  const float* fc = (const float*)d_in[6];
  const float* fs = (const float*)d_in[7];
  float* out = (float*)d_out;

  const size_t bfp = (size_t)NM * NDIM;             // one big plane (elems)
  const size_t kvp = (size_t)NM * NKVD;             // one K/VT plane (elems)
  const size_t qkvB = (size_t)NM * NQKV * 4;        // 50.33 MB equivalent
  const size_t needA = (size_t)(4 * bfp) * 2 + qkvB + (size_t)NQKV * NDIM * 4;  // 218.10 MB
  const size_t needB = (size_t)(4 * bfp) * 2 + qkvB + (size_t)NDIM * NDIM * 4;  // 184.55 MB
  const size_t needC = 2 * bfp * 4 + qkvB;                                       // 117.44 MB

  if (ws_size >= needB) {
    unsigned short* xnh = (unsigned short*)d_ws;
    unsigned short* xnl = xnh + bfp;
    unsigned short* qh  = xnl + bfp;
    unsigned short* ql  = qh + bfp;
    unsigned short* kh  = ql + bfp;
    unsigned short* kl  = kh + kvp;
    unsigned short* vth = kl + kvp;
    unsigned short* vtl = vth + kvp;
    unsigned short* aoh = vtl + kvp;
    unsigned short* aol = aoh + bfp;
    unsigned short* wh  = aol + bfp;

    rmsnorm_k<0><<<NM, 256, 0, stream>>>(x, sc, xnh, xnl, nullptr);

    if (ws_size >= needA) {  // PATH A: fused QKV weight split
      unsigned short* wl = wh + (size_t)NQKV * NDIM;
      splitw_k<<<1024, 256, 0, stream>>>(wq, wh, wl, (long long)NDIM * NDIM / 4);
      splitw_k<<<1024, 256, 0, stream>>>(wk, wh + (size_t)NDIM * NDIM,
                                         wl + (size_t)NDIM * NDIM, (long long)NKVD * NDIM / 4);
      splitw_k<<<1024, 256, 0, stream>>>(wv, wh + (size_t)(NDIM + NKVD) * NDIM,
                                         wl + (size_t)(NDIM + NKVD) * NDIM,
                                         (long long)NKVD * NDIM / 4);
      gemm_split_k<0><<<dim3(NM / 128, NQKV / 128), 256, 0, stream>>>(
          xnh, xnl, wh, wl, fc, fs, nullptr, nullptr, nullptr,
          qh, ql, kh, kl, vth, vtl, 0);
      attn_mfma2_k<<<dim3(NS / 64, NB * NH), 256, 0, stream>>>(
          qh, ql, kh, kl, vth, vtl, aoh, aol);
      splitw_k<<<1024, 256, 0, stream>>>(wo, wh, wl, (long long)NDIM * NDIM / 4);
      gemm_split_k<1><<<dim3(NM / 128, NDIM / 128), 256, 0, stream>>>(
          aoh, aol, wh, wl, nullptr, nullptr, xnh, xnl, out,
          nullptr, nullptr, nullptr, nullptr, nullptr, nullptr, 0);
    } else {  // PATH B: sequenced weight buffer
      unsigned short* wl = wh + (size_t)NDIM * NDIM;
      splitw_k<<<1024, 256, 0, stream>>>(wq, wh, wl, (long long)NDIM * NDIM / 4);
      gemm_split_k<0><<<dim3(NM / 128, NDIM / 128), 256, 0, stream>>>(
          xnh, xnl, wh, wl, fc, fs, nullptr, nullptr, nullptr,
          qh, ql, kh, kl, vth, vtl, 0);
      splitw_k<<<1024, 256, 0, stream>>>(wk, wh, wl, (long long)NKVD * NDIM / 4);
      splitw_k<<<1024, 256, 0, stream>>>(wv, wh + (size_t)NKVD * NDIM,
                                         wl + (size_t)NKVD * NDIM, (long long)NKVD * NDIM / 4);
      gemm_split_k<0><<<dim3(NM / 128, (2 * NKVD) / 128), 256, 0, stream>>>(
          xnh, xnl, wh, wl, fc, fs, nullptr, nullptr, nullptr,
          qh, ql, kh, kl, vth, vtl, NDIM);
      attn_mfma2_k<<<dim3(NS / 64, NB * NH), 256, 0, stream>>>(
          qh, ql, kh, kl, vth, vtl, aoh, aol);
      splitw_k<<<1024, 256, 0, stream>>>(wo, wh, wl, (long long)NDIM * NDIM / 4);
      gemm_split_k<1><<<dim3(NM / 128, NDIM / 128), 256, 0, stream>>>(
          aoh, aol, wh, wl, nullptr, nullptr, xnh, xnl, out,
          nullptr, nullptr, nullptr, nullptr, nullptr, nullptr, 0);
    }
  } else if (ws_size >= needC) {
    // PATH C: fp32 vector fallback
    float* xn   = (float*)d_ws;
    float* qkv  = xn + bfp;
    float* aout = qkv + (size_t)NM * NQKV;

    rmsnorm_k<1><<<NM, 256, 0, stream>>>(x, sc, nullptr, nullptr, xn);
    gemm_f32_k<0><<<dim3(NQKV / FBM, NM / FBM), 256, 0, stream>>>(
        xn, wq, wk, wv, fc, fs, nullptr, qkv);
    attn_f32_k<<<dim3(NS / BQ, NB * NH), 256, 0, stream>>>(qkv, aout);
    gemm_f32_k<1><<<dim3(NDIM / FBM, NM / FBM), 256, 0, stream>>>(
        aout, wo, nullptr, nullptr, nullptr, nullptr, xn, out);
  } else {
    // PATH D: diagnostic clean-fail
    zerofill_k<<<2048, 256, 0, stream>>>(out, (long long)out_size);
  }
}